// Round 9
// baseline (507.210 us; speedup 1.0000x reference)
//
#include <hip/hip_runtime.h>
#include <hip/hip_bf16.h>

// GCN 2-layer encoder: N=100000 nodes, E=3.2M edges, Fin=256, Fh=128, Fo=64.
//   h1 = x@W1 ; a1 = relu(A@h1 + b1) ; h2 = a1@W2 ; out = A@h2 + b2
// A includes self-loops (w=1), symmetric rsqrt-degree normalization.
//
// R9: (a) persistent-block hist+gemm1 fusion: 2048 co-resident blocks
// (8/CU), role fixed per block (896 gemm / 1152 hist, mod-16 interleave),
// each role grid-strides. R7/R8 stripe fusion was ~additive because
// short-lived hist blocks drained while long-lived gemm blocks hoarded CU
// slots; persistent blocks pin the residency ratio. (b) agg1 quarter-wave
// gather (16 lanes x 16B, 8 rows in flight), agg2 eighth-wave (8 lanes x
// 16B, 16 rows in flight). fp16 h1/a1/h2; CSR via packed-u64 atomic.

#define FIN 256
#define FH  128
#define FO  64

#define CNT_SHIFT 42
#define WSCALE 1073741824.0f          // 2^30
#define WINV   (1.0f / 1073741824.0f)
#define LOWMASK ((1ULL << CNT_SHIFT) - 1ULL)

#define NPERS 2048                    // persistent blocks (8/CU x 256 CU)
#define GEMM_PER_16 7                 // 7/16 blocks -> gemm role
#define NG_P (NPERS / 16 * GEMM_PER_16)        // 896 gemm blocks
#define NH_P (NPERS - NG_P)                    // 1152 hist blocks

__device__ __forceinline__ float h2f(unsigned int u16) {
  union { unsigned short s; _Float16 h; } c; c.s = (unsigned short)u16;
  return (float)c.h;
}
__device__ __forceinline__ unsigned int f2h(float f) {
  union { _Float16 h; unsigned short s; } c; c.h = (_Float16)f;  // RNE cvt
  return (unsigned int)c.s;
}

// ---------------- persistent fused: gemm1 role (7/16) + hist role (9/16)
__global__ __launch_bounds__(256) void hist_gemm1_kernel(
    const int* __restrict__ dst, const float* __restrict__ w,
    unsigned long long* __restrict__ cnt64, int* __restrict__ pos, int E,
    const float* __restrict__ X, const float* __restrict__ W,
    unsigned short* __restrict__ H1h, int N, int NBG, int NBH) {
  __shared__ __align__(16) float xs[64][17];
  __shared__ __align__(16) float wsm[16 * FH];
  int bid = blockIdx.x;
  int tid = threadIdx.x;
  int r16 = bid & 15;
  if (r16 >= GEMM_PER_16) {
    // ---- hist role: grid-stride over 256-edge chunks
    int hidx = (bid >> 4) * (16 - GEMM_PER_16) + (r16 - GEMM_PER_16);
    for (int chunk = hidx; chunk < NBH; chunk += NH_P) {
      int e = chunk * 256 + tid;
      if (e < E) {
        int d = dst[e];
        unsigned long long v = (1ULL << CNT_SHIFT)
                             + (unsigned long long)(w[e] * WSCALE);
        unsigned long long old = atomicAdd(&cnt64[d], v);
        pos[e] = (int)(old >> CNT_SHIFT);
      }
    }
    return;
  }
  // ---- gemm role: grid-stride over 64-row tiles
  int gidx = (bid >> 4) * GEMM_PER_16 + r16;
  int tx = tid & 31;        // cols tx*4 .. +3
  int ty = tid >> 5;        // rows ty*8 .. +7
  for (int g = gidx; g < NBG; g += NG_P) {
    int row0 = g * 64;
    float acc[8][4];
    #pragma unroll
    for (int i = 0; i < 8; ++i)
      #pragma unroll
      for (int j = 0; j < 4; ++j) acc[i][j] = 0.f;

    for (int k0 = 0; k0 < FIN; k0 += 16) {
      {
        int rr = tid >> 2, kq = (tid & 3) * 4;
        int gr = row0 + rr;
        float4 v = make_float4(0.f, 0.f, 0.f, 0.f);
        if (gr < N) v = *(const float4*)(X + (size_t)gr * FIN + k0 + kq);
        xs[rr][kq + 0] = v.x; xs[rr][kq + 1] = v.y;
        xs[rr][kq + 2] = v.z; xs[rr][kq + 3] = v.w;
      }
      {
        const float4* s4 = (const float4*)(W + (size_t)k0 * FH);
        float4* d4 = (float4*)wsm;
        d4[tid] = s4[tid];
        d4[tid + 256] = s4[tid + 256];
      }
      __syncthreads();
      #pragma unroll
      for (int kk = 0; kk < 16; ++kk) {
        float xv[8];
        #pragma unroll
        for (int i = 0; i < 8; ++i) xv[i] = xs[ty * 8 + i][kk];
        float4 wv = *(const float4*)(&wsm[kk * FH + tx * 4]);
        #pragma unroll
        for (int i = 0; i < 8; ++i) {
          acc[i][0] += xv[i] * wv.x; acc[i][1] += xv[i] * wv.y;
          acc[i][2] += xv[i] * wv.z; acc[i][3] += xv[i] * wv.w;
        }
      }
      __syncthreads();
    }
    #pragma unroll
    for (int i = 0; i < 8; ++i) {
      int gr = row0 + ty * 8 + i;
      if (gr < N) {
        uint2 pk;
        pk.x = f2h(acc[i][0]) | (f2h(acc[i][1]) << 16);
        pk.y = f2h(acc[i][2]) | (f2h(acc[i][3]) << 16);
        *(uint2*)(H1h + (size_t)gr * FH + tx * 4) = pk;
      }
    }
  }
}

// ---------------- 3-phase exclusive scan of cnt64>>42 -> rowptr; also dinv
__global__ __launch_bounds__(256) void scan1_kernel(
    const unsigned long long* __restrict__ cnt64, int* __restrict__ rowptr,
    int* __restrict__ bsum, float* __restrict__ dinv, int N) {
  __shared__ int tot[256];
  int t = threadIdx.x;
  int base = blockIdx.x * 1024 + t * 4;
  int v0 = 0, v1 = 0, v2 = 0, v3 = 0;
  #pragma unroll
  for (int q = 0; q < 4; ++q) {
    int idx = base + q;
    if (idx < N) {
      unsigned long long c = cnt64[idx];
      int cv = (int)(c >> CNT_SHIFT);
      float deg = (float)(c & LOWMASK) * WINV;
      dinv[idx] = rsqrtf(1.0f + deg);
      if (q == 0) v0 = cv; else if (q == 1) v1 = cv;
      else if (q == 2) v2 = cv; else v3 = cv;
    }
  }
  int s = v0 + v1 + v2 + v3;
  tot[t] = s;
  __syncthreads();
  for (int off = 1; off < 256; off <<= 1) {
    int y = (t >= off) ? tot[t - off] : 0;
    __syncthreads();
    tot[t] += y;
    __syncthreads();
  }
  int p = tot[t] - s;  // exclusive within block
  if (t == 255) bsum[blockIdx.x] = tot[255];
  if (base + 0 < N) rowptr[base + 0] = p; p += v0;
  if (base + 1 < N) rowptr[base + 1] = p; p += v1;
  if (base + 2 < N) rowptr[base + 2] = p; p += v2;
  if (base + 3 < N) rowptr[base + 3] = p;
}

__global__ __launch_bounds__(256) void scan2_kernel(
    int* __restrict__ bsum, int* __restrict__ rowptrN, int nb, int E) {
  __shared__ int buf[256];
  int t = threadIdx.x;
  int v = (t < nb) ? bsum[t] : 0;
  buf[t] = v;
  __syncthreads();
  for (int off = 1; off < 256; off <<= 1) {
    int y = (t >= off) ? buf[t - off] : 0;
    __syncthreads();
    buf[t] += y;
    __syncthreads();
  }
  if (t < nb) bsum[t] = buf[t] - v;  // exclusive
  if (t == 0) rowptrN[0] = E;
}

__global__ __launch_bounds__(256) void scan3_kernel(
    int* __restrict__ rowptr, const int* __restrict__ bsum, int N) {
  int i = blockIdx.x * 256 + threadIdx.x;
  if (i < N) rowptr[i] += bsum[i >> 10];
}

// ---------------- scatter (atomic-free): edges[rowptr[d]+pos[e]] = {src, norm}
__global__ __launch_bounds__(256) void scatter_kernel(
    const int* __restrict__ src, const int* __restrict__ dst,
    const float* __restrict__ w, const int* __restrict__ rowptr,
    const int* __restrict__ pos, const float* __restrict__ dinv,
    int2* __restrict__ edges, int E) {
  int e = blockIdx.x * 256 + threadIdx.x;
  if (e < E) {
    int s = src[e], d = dst[e];
    float nm = dinv[s] * w[e] * dinv[d];
    edges[rowptr[d] + pos[e]] = make_int2(s, __float_as_int(nm));
  }
}

// ---------------- GEMM2: H2h[N,64](fp16) = A1h[N,128](fp16) @ W2[128,64]
__global__ __launch_bounds__(256) void gemm2_kernel(
    const unsigned short* __restrict__ A1h, const float* __restrict__ W2,
    unsigned short* __restrict__ H2h, int N) {
  __shared__ __align__(16) float xs[64][17];
  __shared__ __align__(16) float ws[16 * FO];
  int tid = threadIdx.x;
  int row0 = blockIdx.x * 64;
  int tx = tid & 15;        // cols tx*4..+3
  int ty = tid >> 4;        // rows ty*4..+3
  float acc[4][4];
  #pragma unroll
  for (int i = 0; i < 4; ++i)
    #pragma unroll
    for (int j = 0; j < 4; ++j) acc[i][j] = 0.f;

  for (int k0 = 0; k0 < FH; k0 += 16) {
    {
      int r = tid >> 2, kq = (tid & 3) * 4;
      int gr = row0 + r;
      uint2 v = make_uint2(0u, 0u);
      if (gr < N) v = *(const uint2*)(A1h + (size_t)gr * FH + k0 + kq);
      xs[r][kq + 0] = h2f(v.x & 0xffffu); xs[r][kq + 1] = h2f(v.x >> 16);
      xs[r][kq + 2] = h2f(v.y & 0xffffu); xs[r][kq + 3] = h2f(v.y >> 16);
    }
    {
      const float4* s4 = (const float4*)(W2 + (size_t)k0 * FO);
      float4* d4 = (float4*)ws;
      d4[tid] = s4[tid];
    }
    __syncthreads();
    #pragma unroll
    for (int kk = 0; kk < 16; ++kk) {
      float xv[4];
      #pragma unroll
      for (int i = 0; i < 4; ++i) xv[i] = xs[ty * 4 + i][kk];
      float4 wv = *(const float4*)(&ws[kk * FO + tx * 4]);
      #pragma unroll
      for (int i = 0; i < 4; ++i) {
        acc[i][0] += xv[i] * wv.x; acc[i][1] += xv[i] * wv.y;
        acc[i][2] += xv[i] * wv.z; acc[i][3] += xv[i] * wv.w;
      }
    }
    __syncthreads();
  }
  #pragma unroll
  for (int i = 0; i < 4; ++i) {
    int gr = row0 + ty * 4 + i;
    if (gr < N) {
      uint2 pk;
      pk.x = f2h(acc[i][0]) | (f2h(acc[i][1]) << 16);
      pk.y = f2h(acc[i][2]) | (f2h(acc[i][3]) << 16);
      *(uint2*)(H2h + (size_t)gr * FO + tx * 4) = pk;
    }
  }
}

// ---------------- agg1: a1h = relu(A @ h1 + b1), 128 fp16 feats
// quarter-wave per row: 16 lanes x 16B; 4 edges/wave x2 unroll = 8 in flight
__global__ __launch_bounds__(256) void agg1_kernel(
    const unsigned short* __restrict__ H1h, const int2* __restrict__ edges,
    const int* __restrict__ rowptr, const float* __restrict__ dinv,
    const float* __restrict__ b1, unsigned short* __restrict__ A1h, int N) {
  int wid = (blockIdx.x * 256 + threadIdx.x) >> 6;
  int lane = threadIdx.x & 63;
  if (wid >= N) return;
  int p0 = rowptr[wid], p1 = rowptr[wid + 1];
  int grp = lane >> 4, li = lane & 15;      // li covers feats li*8..+7
  const size_t rowoff = (size_t)li * 8;
  float a0[8], a1[8];
  #pragma unroll
  for (int j = 0; j < 8; ++j) { a0[j] = 0.f; a1[j] = 0.f; }

  int p = p0;
  for (; p + 8 <= p1; p += 8) {
    int2 e0 = edges[p + grp];
    int2 e1 = edges[p + 4 + grp];
    uint4 h0 = *(const uint4*)(H1h + (size_t)e0.x * FH + rowoff);
    uint4 h1 = *(const uint4*)(H1h + (size_t)e1.x * FH + rowoff);
    float n0 = __int_as_float(e0.y), n1 = __int_as_float(e1.y);
    a0[0] += n0 * h2f(h0.x & 0xffffu); a0[1] += n0 * h2f(h0.x >> 16);
    a0[2] += n0 * h2f(h0.y & 0xffffu); a0[3] += n0 * h2f(h0.y >> 16);
    a0[4] += n0 * h2f(h0.z & 0xffffu); a0[5] += n0 * h2f(h0.z >> 16);
    a0[6] += n0 * h2f(h0.w & 0xffffu); a0[7] += n0 * h2f(h0.w >> 16);
    a1[0] += n1 * h2f(h1.x & 0xffffu); a1[1] += n1 * h2f(h1.x >> 16);
    a1[2] += n1 * h2f(h1.y & 0xffffu); a1[3] += n1 * h2f(h1.y >> 16);
    a1[4] += n1 * h2f(h1.z & 0xffffu); a1[5] += n1 * h2f(h1.z >> 16);
    a1[6] += n1 * h2f(h1.w & 0xffffu); a1[7] += n1 * h2f(h1.w >> 16);
  }
  for (; p + 4 <= p1; p += 4) {
    int2 e0 = edges[p + grp];
    uint4 h0 = *(const uint4*)(H1h + (size_t)e0.x * FH + rowoff);
    float n0 = __int_as_float(e0.y);
    a0[0] += n0 * h2f(h0.x & 0xffffu); a0[1] += n0 * h2f(h0.x >> 16);
    a0[2] += n0 * h2f(h0.y & 0xffffu); a0[3] += n0 * h2f(h0.y >> 16);
    a0[4] += n0 * h2f(h0.z & 0xffffu); a0[5] += n0 * h2f(h0.z >> 16);
    a0[6] += n0 * h2f(h0.w & 0xffffu); a0[7] += n0 * h2f(h0.w >> 16);
  }
  if (p < p1) {  // 1..3 leftover edges: masked
    int q = p + grp;
    int qi = (q < p1) ? q : p;
    int2 e0 = edges[qi];
    float n0 = (q < p1) ? __int_as_float(e0.y) : 0.f;
    uint4 h0 = *(const uint4*)(H1h + (size_t)e0.x * FH + rowoff);
    a0[0] += n0 * h2f(h0.x & 0xffffu); a0[1] += n0 * h2f(h0.x >> 16);
    a0[2] += n0 * h2f(h0.y & 0xffffu); a0[3] += n0 * h2f(h0.y >> 16);
    a0[4] += n0 * h2f(h0.z & 0xffffu); a0[5] += n0 * h2f(h0.z >> 16);
    a0[6] += n0 * h2f(h0.w & 0xffffu); a0[7] += n0 * h2f(h0.w >> 16);
  }
  float s[8];
  #pragma unroll
  for (int j = 0; j < 8; ++j) {
    s[j] = a0[j] + a1[j];
    s[j] += __shfl_xor(s[j], 16);
    s[j] += __shfl_xor(s[j], 32);
  }
  if (lane < 16) {
    float di = dinv[wid], sn = di * di;
    uint4 hs = *(const uint4*)(H1h + (size_t)wid * FH + rowoff);
    s[0] += sn * h2f(hs.x & 0xffffu); s[1] += sn * h2f(hs.x >> 16);
    s[2] += sn * h2f(hs.y & 0xffffu); s[3] += sn * h2f(hs.y >> 16);
    s[4] += sn * h2f(hs.z & 0xffffu); s[5] += sn * h2f(hs.z >> 16);
    s[6] += sn * h2f(hs.w & 0xffffu); s[7] += sn * h2f(hs.w >> 16);
    float4 bv0 = *(const float4*)(b1 + li * 8);
    float4 bv1 = *(const float4*)(b1 + li * 8 + 4);
    s[0] = fmaxf(s[0] + bv0.x, 0.f); s[1] = fmaxf(s[1] + bv0.y, 0.f);
    s[2] = fmaxf(s[2] + bv0.z, 0.f); s[3] = fmaxf(s[3] + bv0.w, 0.f);
    s[4] = fmaxf(s[4] + bv1.x, 0.f); s[5] = fmaxf(s[5] + bv1.y, 0.f);
    s[6] = fmaxf(s[6] + bv1.z, 0.f); s[7] = fmaxf(s[7] + bv1.w, 0.f);
    uint4 pk;
    pk.x = f2h(s[0]) | (f2h(s[1]) << 16);
    pk.y = f2h(s[2]) | (f2h(s[3]) << 16);
    pk.z = f2h(s[4]) | (f2h(s[5]) << 16);
    pk.w = f2h(s[6]) | (f2h(s[7]) << 16);
    *(uint4*)(A1h + (size_t)wid * FH + li * 8) = pk;
  }
}

// ---------------- agg2: out = A @ h2 + b2, 64 fp16 feats
// eighth-wave per row: 8 lanes x 16B; 8 edges/wave x2 unroll = 16 in flight
__global__ __launch_bounds__(256) void agg2_kernel(
    const unsigned short* __restrict__ H2h, const int2* __restrict__ edges,
    const int* __restrict__ rowptr, const float* __restrict__ dinv,
    const float* __restrict__ b2, float* __restrict__ OUT, int N) {
  int wid = (blockIdx.x * 256 + threadIdx.x) >> 6;
  int lane = threadIdx.x & 63;
  if (wid >= N) return;
  int p0 = rowptr[wid], p1 = rowptr[wid + 1];
  int grp = lane >> 3, li = lane & 7;       // li covers feats li*8..+7
  const size_t rowoff = (size_t)li * 8;
  float a0[8], a1[8];
  #pragma unroll
  for (int j = 0; j < 8; ++j) { a0[j] = 0.f; a1[j] = 0.f; }

  int p = p0;
  for (; p + 16 <= p1; p += 16) {
    int2 e0 = edges[p + grp];
    int2 e1 = edges[p + 8 + grp];
    uint4 h0 = *(const uint4*)(H2h + (size_t)e0.x * FO + rowoff);
    uint4 h1 = *(const uint4*)(H2h + (size_t)e1.x * FO + rowoff);
    float n0 = __int_as_float(e0.y), n1 = __int_as_float(e1.y);
    a0[0] += n0 * h2f(h0.x & 0xffffu); a0[1] += n0 * h2f(h0.x >> 16);
    a0[2] += n0 * h2f(h0.y & 0xffffu); a0[3] += n0 * h2f(h0.y >> 16);
    a0[4] += n0 * h2f(h0.z & 0xffffu); a0[5] += n0 * h2f(h0.z >> 16);
    a0[6] += n0 * h2f(h0.w & 0xffffu); a0[7] += n0 * h2f(h0.w >> 16);
    a1[0] += n1 * h2f(h1.x & 0xffffu); a1[1] += n1 * h2f(h1.x >> 16);
    a1[2] += n1 * h2f(h1.y & 0xffffu); a1[3] += n1 * h2f(h1.y >> 16);
    a1[4] += n1 * h2f(h1.z & 0xffffu); a1[5] += n1 * h2f(h1.z >> 16);
    a1[6] += n1 * h2f(h1.w & 0xffffu); a1[7] += n1 * h2f(h1.w >> 16);
  }
  for (; p + 8 <= p1; p += 8) {
    int2 e0 = edges[p + grp];
    uint4 h0 = *(const uint4*)(H2h + (size_t)e0.x * FO + rowoff);
    float n0 = __int_as_float(e0.y);
    a0[0] += n0 * h2f(h0.x & 0xffffu); a0[1] += n0 * h2f(h0.x >> 16);
    a0[2] += n0 * h2f(h0.y & 0xffffu); a0[3] += n0 * h2f(h0.y >> 16);
    a0[4] += n0 * h2f(h0.z & 0xffffu); a0[5] += n0 * h2f(h0.z >> 16);
    a0[6] += n0 * h2f(h0.w & 0xffffu); a0[7] += n0 * h2f(h0.w >> 16);
  }
  if (p < p1) {  // 1..7 leftover edges: masked
    int q = p + grp;
    int qi = (q < p1) ? q : p;
    int2 e0 = edges[qi];
    float n0 = (q < p1) ? __int_as_float(e0.y) : 0.f;
    uint4 h0 = *(const uint4*)(H2h + (size_t)e0.x * FO + rowoff);
    a0[0] += n0 * h2f(h0.x & 0xffffu); a0[1] += n0 * h2f(h0.x >> 16);
    a0[2] += n0 * h2f(h0.y & 0xffffu); a0[3] += n0 * h2f(h0.y >> 16);
    a0[4] += n0 * h2f(h0.z & 0xffffu); a0[5] += n0 * h2f(h0.z >> 16);
    a0[6] += n0 * h2f(h0.w & 0xffffu); a0[7] += n0 * h2f(h0.w >> 16);
  }
  float s[8];
  #pragma unroll
  for (int j = 0; j < 8; ++j) {
    s[j] = a0[j] + a1[j];
    s[j] += __shfl_xor(s[j], 8);
    s[j] += __shfl_xor(s[j], 16);
    s[j] += __shfl_xor(s[j], 32);
  }
  if (lane < 8) {
    float di = dinv[wid], sn = di * di;
    uint4 hs = *(const uint4*)(H2h + (size_t)wid * FO + rowoff);
    s[0] += sn * h2f(hs.x & 0xffffu); s[1] += sn * h2f(hs.x >> 16);
    s[2] += sn * h2f(hs.y & 0xffffu); s[3] += sn * h2f(hs.y >> 16);
    s[4] += sn * h2f(hs.z & 0xffffu); s[5] += sn * h2f(hs.z >> 16);
    s[6] += sn * h2f(hs.w & 0xffffu); s[7] += sn * h2f(hs.w >> 16);
    float4 bv0 = *(const float4*)(b2 + li * 8);
    float4 bv1 = *(const float4*)(b2 + li * 8 + 4);
    float4 o0 = make_float4(s[0] + bv0.x, s[1] + bv0.y, s[2] + bv0.z, s[3] + bv0.w);
    float4 o1 = make_float4(s[4] + bv1.x, s[5] + bv1.y, s[6] + bv1.z, s[7] + bv1.w);
    *(float4*)(OUT + (size_t)wid * FO + li * 8) = o0;
    *(float4*)(OUT + (size_t)wid * FO + li * 8 + 4) = o1;
  }
}

extern "C" void kernel_launch(void* const* d_in, const int* in_sizes, int n_in,
                              void* d_out, int out_size, void* d_ws, size_t ws_size,
                              hipStream_t stream) {
  const float* x  = (const float*)d_in[0];
  const int*   ei = (const int*)d_in[1];
  const float* ew = (const float*)d_in[2];
  const float* W1 = (const float*)d_in[3];
  const float* b1 = (const float*)d_in[4];
  const float* W2 = (const float*)d_in[5];
  const float* b2 = (const float*)d_in[6];
  float* out = (float*)d_out;

  const int N = in_sizes[0] / FIN;        // 100000
  const int E = in_sizes[2];              // 3200000
  const int* src = ei;
  const int* dst = ei + E;
  const int nb = (N + 1023) / 1024;       // scan blocks
  const int NBG = (N + 63) / 64;          // gemm1 tiles
  const int NBH = (E + 255) / 256;        // hist chunks

  // workspace layout (16B-aligned slices), ~80MB total
  char* ws = (char*)d_ws;
  size_t off = 0;
  unsigned short* h1h = (unsigned short*)(ws + off); off += (size_t)N * FH * 2;  // fp16 h1
  unsigned short* h2h = (unsigned short*)(ws + off); off += (size_t)N * FO * 2;  // fp16 h2
  unsigned short* a1h = (unsigned short*)(ws + off); off += (size_t)N * FH * 2;  // fp16 a1
  int2*  edges  = (int2*) (ws + off); off += (size_t)E * 8;
  int*   pos    = (int*)  (ws + off); off += (size_t)E * 4;
  unsigned long long* cnt64 = (unsigned long long*)(ws + off); off += (size_t)N * 8;
  int*   rowptr = (int*)  (ws + off); off += (((size_t)(N + 1) * 4) + 15) & ~(size_t)15;
  float* dinv   = (float*)(ws + off); off += (size_t)N * 4;
  int*   bsum   = (int*)  (ws + off); off += 1024;

  hipMemsetAsync(cnt64, 0, (size_t)N * 8, stream);
  hist_gemm1_kernel<<<NPERS, 256, 0, stream>>>(dst, ew, cnt64, pos, E,
                                               x, W1, h1h, N, NBG, NBH);
  scan1_kernel<<<nb, 256, 0, stream>>>(cnt64, rowptr, bsum, dinv, N);
  scan2_kernel<<<1, 256, 0, stream>>>(bsum, rowptr + N, nb, E);
  scan3_kernel<<<(N + 255) / 256, 256, 0, stream>>>(rowptr, bsum, N);
  scatter_kernel<<<(E + 255) / 256, 256, 0, stream>>>(src, dst, ew, rowptr, pos,
                                                      dinv, edges, E);
  agg1_kernel<<<(N * 64 + 255) / 256, 256, 0, stream>>>(h1h, edges, rowptr,
                                                        dinv, b1, a1h, N);
  gemm2_kernel<<<(N + 63) / 64, 256, 0, stream>>>(a1h, W2, h2h, N);
  agg2_kernel<<<(N * 64 + 255) / 256, 256, 0, stream>>>(h2h, edges, rowptr,
                                                        dinv, b2, out, N);
}

// Round 10
// 487.652 us; speedup vs baseline: 1.0401x; 1.0401x over previous
//
#include <hip/hip_runtime.h>
#include <hip/hip_bf16.h>

// GCN 2-layer encoder: N=100000 nodes, E=3.2M edges, Fin=256, Fh=128, Fo=64.
//   h1 = x@W1 ; a1 = relu(A@h1 + b1) ; h2 = a1@W2 ; out = A@h2 + b2
// A includes self-loops (w=1), symmetric rsqrt-degree normalization.
//
// R10 = best-of(R8, R9): stripe-interleaved hist+gemm1 (R8, 195us measured;
// R9's persistent grid-stride variant regressed to 247us -- per-wave atomic
// round-trips serialize) + quarter-wave agg1 / eighth-wave agg2 (R9, -37us).
// fp16 h1/a1/h2; CSR via packed-u64 atomic (count<<42 | fixed-point wdeg;
// returned old>>42 = stable in-row position; scatter atomic-free).

#define FIN 256
#define FH  128
#define FO  64

#define CNT_SHIFT 42
#define WSCALE 1073741824.0f          // 2^30
#define WINV   (1.0f / 1073741824.0f)
#define LOWMASK ((1ULL << CNT_SHIFT) - 1ULL)
#define RATIO 8                        // hist blocks per gemm block (12500:1563)

__device__ __forceinline__ float h2f(unsigned int u16) {
  union { unsigned short s; _Float16 h; } c; c.s = (unsigned short)u16;
  return (float)c.h;
}
__device__ __forceinline__ unsigned int f2h(float f) {
  union { _Float16 h; unsigned short s; } c; c.h = (_Float16)f;  // RNE cvt
  return (unsigned int)c.s;
}

// ---------------- fused: stripe-interleaved hist (8/9) + gemm1 (1/9)
__global__ __launch_bounds__(256) void hist_gemm1_kernel(
    const int* __restrict__ dst, const float* __restrict__ w,
    unsigned long long* __restrict__ cnt64, int* __restrict__ pos, int E,
    const float* __restrict__ X, const float* __restrict__ W,
    unsigned short* __restrict__ H1h, int N, int NBG) {
  __shared__ __align__(16) float xs[64][17];
  __shared__ __align__(16) float wsm[16 * FH];
  int bid = blockIdx.x;
  int tid = threadIdx.x;
  int g = bid / (RATIO + 1);
  int r = bid - g * (RATIO + 1);
  if (r != RATIO) {
    // ---- histogram role: one u64 atomic per edge; returns stable position
    int e = (g * RATIO + r) * 256 + tid;
    if (e < E) {
      int d = dst[e];
      unsigned long long v = (1ULL << CNT_SHIFT)
                           + (unsigned long long)(w[e] * WSCALE);
      unsigned long long old = atomicAdd(&cnt64[d], v);
      pos[e] = (int)(old >> CNT_SHIFT);
    }
    return;
  }
  if (g >= NBG) return;
  // ---- gemm1 role: H1h[64 rows, 128 cols] fp16 = X @ W1
  int row0 = g * 64;
  int tx = tid & 31;        // cols tx*4 .. +3
  int ty = tid >> 5;        // rows ty*8 .. +7
  float acc[8][4];
  #pragma unroll
  for (int i = 0; i < 8; ++i)
    #pragma unroll
    for (int j = 0; j < 4; ++j) acc[i][j] = 0.f;

  for (int k0 = 0; k0 < FIN; k0 += 16) {
    {
      int rr = tid >> 2, kq = (tid & 3) * 4;
      int gr = row0 + rr;
      float4 v = make_float4(0.f, 0.f, 0.f, 0.f);
      if (gr < N) v = *(const float4*)(X + (size_t)gr * FIN + k0 + kq);
      xs[rr][kq + 0] = v.x; xs[rr][kq + 1] = v.y;
      xs[rr][kq + 2] = v.z; xs[rr][kq + 3] = v.w;
    }
    {
      const float4* s4 = (const float4*)(W + (size_t)k0 * FH);
      float4* d4 = (float4*)wsm;
      d4[tid] = s4[tid];
      d4[tid + 256] = s4[tid + 256];
    }
    __syncthreads();
    #pragma unroll
    for (int kk = 0; kk < 16; ++kk) {
      float xv[8];
      #pragma unroll
      for (int i = 0; i < 8; ++i) xv[i] = xs[ty * 8 + i][kk];
      float4 wv = *(const float4*)(&wsm[kk * FH + tx * 4]);
      #pragma unroll
      for (int i = 0; i < 8; ++i) {
        acc[i][0] += xv[i] * wv.x; acc[i][1] += xv[i] * wv.y;
        acc[i][2] += xv[i] * wv.z; acc[i][3] += xv[i] * wv.w;
      }
    }
    __syncthreads();
  }
  #pragma unroll
  for (int i = 0; i < 8; ++i) {
    int gr = row0 + ty * 8 + i;
    if (gr < N) {
      uint2 pk;
      pk.x = f2h(acc[i][0]) | (f2h(acc[i][1]) << 16);
      pk.y = f2h(acc[i][2]) | (f2h(acc[i][3]) << 16);
      *(uint2*)(H1h + (size_t)gr * FH + tx * 4) = pk;
    }
  }
}

// ---------------- 3-phase exclusive scan of cnt64>>42 -> rowptr; also dinv
__global__ __launch_bounds__(256) void scan1_kernel(
    const unsigned long long* __restrict__ cnt64, int* __restrict__ rowptr,
    int* __restrict__ bsum, float* __restrict__ dinv, int N) {
  __shared__ int tot[256];
  int t = threadIdx.x;
  int base = blockIdx.x * 1024 + t * 4;
  int v0 = 0, v1 = 0, v2 = 0, v3 = 0;
  #pragma unroll
  for (int q = 0; q < 4; ++q) {
    int idx = base + q;
    if (idx < N) {
      unsigned long long c = cnt64[idx];
      int cv = (int)(c >> CNT_SHIFT);
      float deg = (float)(c & LOWMASK) * WINV;
      dinv[idx] = rsqrtf(1.0f + deg);
      if (q == 0) v0 = cv; else if (q == 1) v1 = cv;
      else if (q == 2) v2 = cv; else v3 = cv;
    }
  }
  int s = v0 + v1 + v2 + v3;
  tot[t] = s;
  __syncthreads();
  for (int off = 1; off < 256; off <<= 1) {
    int y = (t >= off) ? tot[t - off] : 0;
    __syncthreads();
    tot[t] += y;
    __syncthreads();
  }
  int p = tot[t] - s;  // exclusive within block
  if (t == 255) bsum[blockIdx.x] = tot[255];
  if (base + 0 < N) rowptr[base + 0] = p; p += v0;
  if (base + 1 < N) rowptr[base + 1] = p; p += v1;
  if (base + 2 < N) rowptr[base + 2] = p; p += v2;
  if (base + 3 < N) rowptr[base + 3] = p;
}

__global__ __launch_bounds__(256) void scan2_kernel(
    int* __restrict__ bsum, int* __restrict__ rowptrN, int nb, int E) {
  __shared__ int buf[256];
  int t = threadIdx.x;
  int v = (t < nb) ? bsum[t] : 0;
  buf[t] = v;
  __syncthreads();
  for (int off = 1; off < 256; off <<= 1) {
    int y = (t >= off) ? buf[t - off] : 0;
    __syncthreads();
    buf[t] += y;
    __syncthreads();
  }
  if (t < nb) bsum[t] = buf[t] - v;  // exclusive
  if (t == 0) rowptrN[0] = E;
}

__global__ __launch_bounds__(256) void scan3_kernel(
    int* __restrict__ rowptr, const int* __restrict__ bsum, int N) {
  int i = blockIdx.x * 256 + threadIdx.x;
  if (i < N) rowptr[i] += bsum[i >> 10];
}

// ---------------- scatter (atomic-free): edges[rowptr[d]+pos[e]] = {src, norm}
__global__ __launch_bounds__(256) void scatter_kernel(
    const int* __restrict__ src, const int* __restrict__ dst,
    const float* __restrict__ w, const int* __restrict__ rowptr,
    const int* __restrict__ pos, const float* __restrict__ dinv,
    int2* __restrict__ edges, int E) {
  int e = blockIdx.x * 256 + threadIdx.x;
  if (e < E) {
    int s = src[e], d = dst[e];
    float nm = dinv[s] * w[e] * dinv[d];
    edges[rowptr[d] + pos[e]] = make_int2(s, __float_as_int(nm));
  }
}

// ---------------- GEMM2: H2h[N,64](fp16) = A1h[N,128](fp16) @ W2[128,64]
__global__ __launch_bounds__(256) void gemm2_kernel(
    const unsigned short* __restrict__ A1h, const float* __restrict__ W2,
    unsigned short* __restrict__ H2h, int N) {
  __shared__ __align__(16) float xs[64][17];
  __shared__ __align__(16) float ws[16 * FO];
  int tid = threadIdx.x;
  int row0 = blockIdx.x * 64;
  int tx = tid & 15;        // cols tx*4..+3
  int ty = tid >> 4;        // rows ty*4..+3
  float acc[4][4];
  #pragma unroll
  for (int i = 0; i < 4; ++i)
    #pragma unroll
    for (int j = 0; j < 4; ++j) acc[i][j] = 0.f;

  for (int k0 = 0; k0 < FH; k0 += 16) {
    {
      int r = tid >> 2, kq = (tid & 3) * 4;
      int gr = row0 + r;
      uint2 v = make_uint2(0u, 0u);
      if (gr < N) v = *(const uint2*)(A1h + (size_t)gr * FH + k0 + kq);
      xs[r][kq + 0] = h2f(v.x & 0xffffu); xs[r][kq + 1] = h2f(v.x >> 16);
      xs[r][kq + 2] = h2f(v.y & 0xffffu); xs[r][kq + 3] = h2f(v.y >> 16);
    }
    {
      const float4* s4 = (const float4*)(W2 + (size_t)k0 * FO);
      float4* d4 = (float4*)ws;
      d4[tid] = s4[tid];
    }
    __syncthreads();
    #pragma unroll
    for (int kk = 0; kk < 16; ++kk) {
      float xv[4];
      #pragma unroll
      for (int i = 0; i < 4; ++i) xv[i] = xs[ty * 4 + i][kk];
      float4 wv = *(const float4*)(&ws[kk * FO + tx * 4]);
      #pragma unroll
      for (int i = 0; i < 4; ++i) {
        acc[i][0] += xv[i] * wv.x; acc[i][1] += xv[i] * wv.y;
        acc[i][2] += xv[i] * wv.z; acc[i][3] += xv[i] * wv.w;
      }
    }
    __syncthreads();
  }
  #pragma unroll
  for (int i = 0; i < 4; ++i) {
    int gr = row0 + ty * 4 + i;
    if (gr < N) {
      uint2 pk;
      pk.x = f2h(acc[i][0]) | (f2h(acc[i][1]) << 16);
      pk.y = f2h(acc[i][2]) | (f2h(acc[i][3]) << 16);
      *(uint2*)(H2h + (size_t)gr * FO + tx * 4) = pk;
    }
  }
}

// ---------------- agg1: a1h = relu(A @ h1 + b1), 128 fp16 feats
// quarter-wave per row: 16 lanes x 16B; 4 edges/wave x2 unroll = 8 in flight
__global__ __launch_bounds__(256) void agg1_kernel(
    const unsigned short* __restrict__ H1h, const int2* __restrict__ edges,
    const int* __restrict__ rowptr, const float* __restrict__ dinv,
    const float* __restrict__ b1, unsigned short* __restrict__ A1h, int N) {
  int wid = (blockIdx.x * 256 + threadIdx.x) >> 6;
  int lane = threadIdx.x & 63;
  if (wid >= N) return;
  int p0 = rowptr[wid], p1 = rowptr[wid + 1];
  int grp = lane >> 4, li = lane & 15;      // li covers feats li*8..+7
  const size_t rowoff = (size_t)li * 8;
  float a0[8], a1[8];
  #pragma unroll
  for (int j = 0; j < 8; ++j) { a0[j] = 0.f; a1[j] = 0.f; }

  int p = p0;
  for (; p + 8 <= p1; p += 8) {
    int2 e0 = edges[p + grp];
    int2 e1 = edges[p + 4 + grp];
    uint4 h0 = *(const uint4*)(H1h + (size_t)e0.x * FH + rowoff);
    uint4 h1 = *(const uint4*)(H1h + (size_t)e1.x * FH + rowoff);
    float n0 = __int_as_float(e0.y), n1 = __int_as_float(e1.y);
    a0[0] += n0 * h2f(h0.x & 0xffffu); a0[1] += n0 * h2f(h0.x >> 16);
    a0[2] += n0 * h2f(h0.y & 0xffffu); a0[3] += n0 * h2f(h0.y >> 16);
    a0[4] += n0 * h2f(h0.z & 0xffffu); a0[5] += n0 * h2f(h0.z >> 16);
    a0[6] += n0 * h2f(h0.w & 0xffffu); a0[7] += n0 * h2f(h0.w >> 16);
    a1[0] += n1 * h2f(h1.x & 0xffffu); a1[1] += n1 * h2f(h1.x >> 16);
    a1[2] += n1 * h2f(h1.y & 0xffffu); a1[3] += n1 * h2f(h1.y >> 16);
    a1[4] += n1 * h2f(h1.z & 0xffffu); a1[5] += n1 * h2f(h1.z >> 16);
    a1[6] += n1 * h2f(h1.w & 0xffffu); a1[7] += n1 * h2f(h1.w >> 16);
  }
  for (; p + 4 <= p1; p += 4) {
    int2 e0 = edges[p + grp];
    uint4 h0 = *(const uint4*)(H1h + (size_t)e0.x * FH + rowoff);
    float n0 = __int_as_float(e0.y);
    a0[0] += n0 * h2f(h0.x & 0xffffu); a0[1] += n0 * h2f(h0.x >> 16);
    a0[2] += n0 * h2f(h0.y & 0xffffu); a0[3] += n0 * h2f(h0.y >> 16);
    a0[4] += n0 * h2f(h0.z & 0xffffu); a0[5] += n0 * h2f(h0.z >> 16);
    a0[6] += n0 * h2f(h0.w & 0xffffu); a0[7] += n0 * h2f(h0.w >> 16);
  }
  if (p < p1) {  // 1..3 leftover edges: masked
    int q = p + grp;
    int qi = (q < p1) ? q : p;
    int2 e0 = edges[qi];
    float n0 = (q < p1) ? __int_as_float(e0.y) : 0.f;
    uint4 h0 = *(const uint4*)(H1h + (size_t)e0.x * FH + rowoff);
    a0[0] += n0 * h2f(h0.x & 0xffffu); a0[1] += n0 * h2f(h0.x >> 16);
    a0[2] += n0 * h2f(h0.y & 0xffffu); a0[3] += n0 * h2f(h0.y >> 16);
    a0[4] += n0 * h2f(h0.z & 0xffffu); a0[5] += n0 * h2f(h0.z >> 16);
    a0[6] += n0 * h2f(h0.w & 0xffffu); a0[7] += n0 * h2f(h0.w >> 16);
  }
  float s[8];
  #pragma unroll
  for (int j = 0; j < 8; ++j) {
    s[j] = a0[j] + a1[j];
    s[j] += __shfl_xor(s[j], 16);
    s[j] += __shfl_xor(s[j], 32);
  }
  if (lane < 16) {
    float di = dinv[wid], sn = di * di;
    uint4 hs = *(const uint4*)(H1h + (size_t)wid * FH + rowoff);
    s[0] += sn * h2f(hs.x & 0xffffu); s[1] += sn * h2f(hs.x >> 16);
    s[2] += sn * h2f(hs.y & 0xffffu); s[3] += sn * h2f(hs.y >> 16);
    s[4] += sn * h2f(hs.z & 0xffffu); s[5] += sn * h2f(hs.z >> 16);
    s[6] += sn * h2f(hs.w & 0xffffu); s[7] += sn * h2f(hs.w >> 16);
    float4 bv0 = *(const float4*)(b1 + li * 8);
    float4 bv1 = *(const float4*)(b1 + li * 8 + 4);
    s[0] = fmaxf(s[0] + bv0.x, 0.f); s[1] = fmaxf(s[1] + bv0.y, 0.f);
    s[2] = fmaxf(s[2] + bv0.z, 0.f); s[3] = fmaxf(s[3] + bv0.w, 0.f);
    s[4] = fmaxf(s[4] + bv1.x, 0.f); s[5] = fmaxf(s[5] + bv1.y, 0.f);
    s[6] = fmaxf(s[6] + bv1.z, 0.f); s[7] = fmaxf(s[7] + bv1.w, 0.f);
    uint4 pk;
    pk.x = f2h(s[0]) | (f2h(s[1]) << 16);
    pk.y = f2h(s[2]) | (f2h(s[3]) << 16);
    pk.z = f2h(s[4]) | (f2h(s[5]) << 16);
    pk.w = f2h(s[6]) | (f2h(s[7]) << 16);
    *(uint4*)(A1h + (size_t)wid * FH + li * 8) = pk;
  }
}

// ---------------- agg2: out = A @ h2 + b2, 64 fp16 feats
// eighth-wave per row: 8 lanes x 16B; 8 edges/wave x2 unroll = 16 in flight
__global__ __launch_bounds__(256) void agg2_kernel(
    const unsigned short* __restrict__ H2h, const int2* __restrict__ edges,
    const int* __restrict__ rowptr, const float* __restrict__ dinv,
    const float* __restrict__ b2, float* __restrict__ OUT, int N) {
  int wid = (blockIdx.x * 256 + threadIdx.x) >> 6;
  int lane = threadIdx.x & 63;
  if (wid >= N) return;
  int p0 = rowptr[wid], p1 = rowptr[wid + 1];
  int grp = lane >> 3, li = lane & 7;       // li covers feats li*8..+7
  const size_t rowoff = (size_t)li * 8;
  float a0[8], a1[8];
  #pragma unroll
  for (int j = 0; j < 8; ++j) { a0[j] = 0.f; a1[j] = 0.f; }

  int p = p0;
  for (; p + 16 <= p1; p += 16) {
    int2 e0 = edges[p + grp];
    int2 e1 = edges[p + 8 + grp];
    uint4 h0 = *(const uint4*)(H2h + (size_t)e0.x * FO + rowoff);
    uint4 h1 = *(const uint4*)(H2h + (size_t)e1.x * FO + rowoff);
    float n0 = __int_as_float(e0.y), n1 = __int_as_float(e1.y);
    a0[0] += n0 * h2f(h0.x & 0xffffu); a0[1] += n0 * h2f(h0.x >> 16);
    a0[2] += n0 * h2f(h0.y & 0xffffu); a0[3] += n0 * h2f(h0.y >> 16);
    a0[4] += n0 * h2f(h0.z & 0xffffu); a0[5] += n0 * h2f(h0.z >> 16);
    a0[6] += n0 * h2f(h0.w & 0xffffu); a0[7] += n0 * h2f(h0.w >> 16);
    a1[0] += n1 * h2f(h1.x & 0xffffu); a1[1] += n1 * h2f(h1.x >> 16);
    a1[2] += n1 * h2f(h1.y & 0xffffu); a1[3] += n1 * h2f(h1.y >> 16);
    a1[4] += n1 * h2f(h1.z & 0xffffu); a1[5] += n1 * h2f(h1.z >> 16);
    a1[6] += n1 * h2f(h1.w & 0xffffu); a1[7] += n1 * h2f(h1.w >> 16);
  }
  for (; p + 8 <= p1; p += 8) {
    int2 e0 = edges[p + grp];
    uint4 h0 = *(const uint4*)(H2h + (size_t)e0.x * FO + rowoff);
    float n0 = __int_as_float(e0.y);
    a0[0] += n0 * h2f(h0.x & 0xffffu); a0[1] += n0 * h2f(h0.x >> 16);
    a0[2] += n0 * h2f(h0.y & 0xffffu); a0[3] += n0 * h2f(h0.y >> 16);
    a0[4] += n0 * h2f(h0.z & 0xffffu); a0[5] += n0 * h2f(h0.z >> 16);
    a0[6] += n0 * h2f(h0.w & 0xffffu); a0[7] += n0 * h2f(h0.w >> 16);
  }
  if (p < p1) {  // 1..7 leftover edges: masked
    int q = p + grp;
    int qi = (q < p1) ? q : p;
    int2 e0 = edges[qi];
    float n0 = (q < p1) ? __int_as_float(e0.y) : 0.f;
    uint4 h0 = *(const uint4*)(H2h + (size_t)e0.x * FO + rowoff);
    a0[0] += n0 * h2f(h0.x & 0xffffu); a0[1] += n0 * h2f(h0.x >> 16);
    a0[2] += n0 * h2f(h0.y & 0xffffu); a0[3] += n0 * h2f(h0.y >> 16);
    a0[4] += n0 * h2f(h0.z & 0xffffu); a0[5] += n0 * h2f(h0.z >> 16);
    a0[6] += n0 * h2f(h0.w & 0xffffu); a0[7] += n0 * h2f(h0.w >> 16);
  }
  float s[8];
  #pragma unroll
  for (int j = 0; j < 8; ++j) {
    s[j] = a0[j] + a1[j];
    s[j] += __shfl_xor(s[j], 8);
    s[j] += __shfl_xor(s[j], 16);
    s[j] += __shfl_xor(s[j], 32);
  }
  if (lane < 8) {
    float di = dinv[wid], sn = di * di;
    uint4 hs = *(const uint4*)(H2h + (size_t)wid * FO + rowoff);
    s[0] += sn * h2f(hs.x & 0xffffu); s[1] += sn * h2f(hs.x >> 16);
    s[2] += sn * h2f(hs.y & 0xffffu); s[3] += sn * h2f(hs.y >> 16);
    s[4] += sn * h2f(hs.z & 0xffffu); s[5] += sn * h2f(hs.z >> 16);
    s[6] += sn * h2f(hs.w & 0xffffu); s[7] += sn * h2f(hs.w >> 16);
    float4 bv0 = *(const float4*)(b2 + li * 8);
    float4 bv1 = *(const float4*)(b2 + li * 8 + 4);
    float4 o0 = make_float4(s[0] + bv0.x, s[1] + bv0.y, s[2] + bv0.z, s[3] + bv0.w);
    float4 o1 = make_float4(s[4] + bv1.x, s[5] + bv1.y, s[6] + bv1.z, s[7] + bv1.w);
    *(float4*)(OUT + (size_t)wid * FO + li * 8) = o0;
    *(float4*)(OUT + (size_t)wid * FO + li * 8 + 4) = o1;
  }
}

extern "C" void kernel_launch(void* const* d_in, const int* in_sizes, int n_in,
                              void* d_out, int out_size, void* d_ws, size_t ws_size,
                              hipStream_t stream) {
  const float* x  = (const float*)d_in[0];
  const int*   ei = (const int*)d_in[1];
  const float* ew = (const float*)d_in[2];
  const float* W1 = (const float*)d_in[3];
  const float* b1 = (const float*)d_in[4];
  const float* W2 = (const float*)d_in[5];
  const float* b2 = (const float*)d_in[6];
  float* out = (float*)d_out;

  const int N = in_sizes[0] / FIN;        // 100000
  const int E = in_sizes[2];              // 3200000
  const int* src = ei;
  const int* dst = ei + E;
  const int nb = (N + 1023) / 1024;       // scan blocks
  const int NBG = (N + 63) / 64;          // gemm1 tiles
  const int NBH = (E + 255) / 256;        // hist chunks
  // stripe-interleaved grid: bid%9==8 -> gemm g=bid/9; else hist (bid/9)*8+bid%9
  int bidH = ((NBH - 1) / RATIO) * (RATIO + 1) + ((NBH - 1) % RATIO);
  int bidG = (NBG - 1) * (RATIO + 1) + RATIO;
  int GRID = (bidH > bidG ? bidH : bidG) + 1;

  // workspace layout (16B-aligned slices), ~80MB total
  char* ws = (char*)d_ws;
  size_t off = 0;
  unsigned short* h1h = (unsigned short*)(ws + off); off += (size_t)N * FH * 2;  // fp16 h1
  unsigned short* h2h = (unsigned short*)(ws + off); off += (size_t)N * FO * 2;  // fp16 h2
  unsigned short* a1h = (unsigned short*)(ws + off); off += (size_t)N * FH * 2;  // fp16 a1
  int2*  edges  = (int2*) (ws + off); off += (size_t)E * 8;
  int*   pos    = (int*)  (ws + off); off += (size_t)E * 4;
  unsigned long long* cnt64 = (unsigned long long*)(ws + off); off += (size_t)N * 8;
  int*   rowptr = (int*)  (ws + off); off += (((size_t)(N + 1) * 4) + 15) & ~(size_t)15;
  float* dinv   = (float*)(ws + off); off += (size_t)N * 4;
  int*   bsum   = (int*)  (ws + off); off += 1024;

  hipMemsetAsync(cnt64, 0, (size_t)N * 8, stream);
  hist_gemm1_kernel<<<GRID, 256, 0, stream>>>(dst, ew, cnt64, pos, E,
                                              x, W1, h1h, N, NBG);
  scan1_kernel<<<nb, 256, 0, stream>>>(cnt64, rowptr, bsum, dinv, N);
  scan2_kernel<<<1, 256, 0, stream>>>(bsum, rowptr + N, nb, E);
  scan3_kernel<<<(N + 255) / 256, 256, 0, stream>>>(rowptr, bsum, N);
  scatter_kernel<<<(E + 255) / 256, 256, 0, stream>>>(src, dst, ew, rowptr, pos,
                                                      dinv, edges, E);
  agg1_kernel<<<(N * 64 + 255) / 256, 256, 0, stream>>>(h1h, edges, rowptr,
                                                        dinv, b1, a1h, N);
  gemm2_kernel<<<(N + 63) / 64, 256, 0, stream>>>(a1h, W2, h2h, N);
  agg2_kernel<<<(N * 64 + 255) / 256, 256, 0, stream>>>(h2h, edges, rowptr,
                                                        dinv, b2, out, N);
}

// Round 11
// 450.409 us; speedup vs baseline: 1.1261x; 1.0827x over previous
//
#include <hip/hip_runtime.h>
#include <hip/hip_bf16.h>

// GCN 2-layer encoder: N=100000 nodes, E=3.2M edges, Fin=256, Fh=128, Fo=64.
//   h1 = x@W1 ; a1 = relu(A@h1 + b1) ; h2 = a1@W2 ; out = A@h2 + b2
// A includes self-loops (w=1), symmetric rsqrt-degree normalization.
//
// R11: bucketed CSR build replaces the device-atomic histogram (device
// atomics cap at ~21G/s regardless of width => 152us floor; LDS atomics
// sidestep the fabric). Bucket = dst>>8 (391 buckets x 256 nodes):
//   A1 (fused w/ gemm1): per-block LDS hist -> gtable[bucket][block]
//   scan (3-phase, in-place over 153K)      -> global offsets
//   A3: re-read edges, LDS rank, scatter packed {w|l|src} bucket-major
//   B1: block/bucket LDS count+fx-degree -> rowptr + dinv
//   B2: block/bucket LDS rank -> CSR edges {src, norm} (L2-dense writes)
// agg1/gemm2/agg2 unchanged from R10. fp16 h1/a1/h2.

#define FIN 256
#define FH  128
#define FO  64

#define EBLK 8192                     // edges per A-phase block (256 thr x 32)
#define WFX  33554432.0f              // 2^25 fixed-point degree scale
#define WFXI (1.0f / 33554432.0f)

__device__ __forceinline__ float h2f(unsigned int u16) {
  union { unsigned short s; _Float16 h; } c; c.s = (unsigned short)u16;
  return (float)c.h;
}
__device__ __forceinline__ unsigned int f2h(float f) {
  union { _Float16 h; unsigned short s; } c; c.h = (_Float16)f;  // RNE cvt
  return (unsigned int)c.s;
}

// ---------------- A1 (blocks [0,NBA)) + gemm1 (blocks [NBA, NBA+NBG))
__global__ __launch_bounds__(256) void a1hist_gemm1_kernel(
    const int* __restrict__ dst, int* __restrict__ gtable, int E,
    int NBA, int NB,
    const float* __restrict__ X, const float* __restrict__ W,
    unsigned short* __restrict__ H1h, int N, int NBG) {
  __shared__ __align__(16) float xs[64][17];
  __shared__ __align__(16) float wsm[16 * FH];
  __shared__ unsigned int bh[392];
  int bid = blockIdx.x;
  int tid = threadIdx.x;
  if (bid < NBA) {
    // ---- bucket-histogram role
    for (int k = tid; k < NB; k += 256) bh[k] = 0u;
    __syncthreads();
    int e0 = bid * EBLK;
    #pragma unroll 4
    for (int it = 0; it < EBLK / 256; ++it) {
      int e = e0 + it * 256 + tid;
      if (e < E) atomicAdd(&bh[dst[e] >> 8], 1u);
    }
    __syncthreads();
    for (int k = tid; k < NB; k += 256)
      gtable[k * NBA + bid] = (int)bh[k];
    return;
  }
  int g = bid - NBA;
  if (g >= NBG) return;
  // ---- gemm1 role: H1h[64 rows, 128 cols] fp16 = X @ W1
  int row0 = g * 64;
  int tx = tid & 31;        // cols tx*4 .. +3
  int ty = tid >> 5;        // rows ty*8 .. +7
  float acc[8][4];
  #pragma unroll
  for (int i = 0; i < 8; ++i)
    #pragma unroll
    for (int j = 0; j < 4; ++j) acc[i][j] = 0.f;

  for (int k0 = 0; k0 < FIN; k0 += 16) {
    {
      int rr = tid >> 2, kq = (tid & 3) * 4;
      int gr = row0 + rr;
      float4 v = make_float4(0.f, 0.f, 0.f, 0.f);
      if (gr < N) v = *(const float4*)(X + (size_t)gr * FIN + k0 + kq);
      xs[rr][kq + 0] = v.x; xs[rr][kq + 1] = v.y;
      xs[rr][kq + 2] = v.z; xs[rr][kq + 3] = v.w;
    }
    {
      const float4* s4 = (const float4*)(W + (size_t)k0 * FH);
      float4* d4 = (float4*)wsm;
      d4[tid] = s4[tid];
      d4[tid + 256] = s4[tid + 256];
    }
    __syncthreads();
    #pragma unroll
    for (int kk = 0; kk < 16; ++kk) {
      float xv[8];
      #pragma unroll
      for (int i = 0; i < 8; ++i) xv[i] = xs[ty * 8 + i][kk];
      float4 wv = *(const float4*)(&wsm[kk * FH + tx * 4]);
      #pragma unroll
      for (int i = 0; i < 8; ++i) {
        acc[i][0] += xv[i] * wv.x; acc[i][1] += xv[i] * wv.y;
        acc[i][2] += xv[i] * wv.z; acc[i][3] += xv[i] * wv.w;
      }
    }
    __syncthreads();
  }
  #pragma unroll
  for (int i = 0; i < 8; ++i) {
    int gr = row0 + ty * 8 + i;
    if (gr < N) {
      uint2 pk;
      pk.x = f2h(acc[i][0]) | (f2h(acc[i][1]) << 16);
      pk.y = f2h(acc[i][2]) | (f2h(acc[i][3]) << 16);
      *(uint2*)(H1h + (size_t)gr * FH + tx * 4) = pk;
    }
  }
}

// ---------------- 3-phase exclusive scan, in-place on int array of length L
__global__ __launch_bounds__(256) void scan1i_kernel(
    int* __restrict__ arr, int* __restrict__ bsum, int L) {
  __shared__ int tot[256];
  int t = threadIdx.x;
  int base = blockIdx.x * 1024 + t * 4;
  int v0 = (base + 0 < L) ? arr[base + 0] : 0;
  int v1 = (base + 1 < L) ? arr[base + 1] : 0;
  int v2 = (base + 2 < L) ? arr[base + 2] : 0;
  int v3 = (base + 3 < L) ? arr[base + 3] : 0;
  int s = v0 + v1 + v2 + v3;
  tot[t] = s;
  __syncthreads();
  for (int off = 1; off < 256; off <<= 1) {
    int y = (t >= off) ? tot[t - off] : 0;
    __syncthreads();
    tot[t] += y;
    __syncthreads();
  }
  int p = tot[t] - s;  // exclusive within block
  if (t == 255) bsum[blockIdx.x] = tot[255];
  if (base + 0 < L) arr[base + 0] = p; p += v0;
  if (base + 1 < L) arr[base + 1] = p; p += v1;
  if (base + 2 < L) arr[base + 2] = p; p += v2;
  if (base + 3 < L) arr[base + 3] = p;
}

__global__ __launch_bounds__(256) void scan2_kernel(
    int* __restrict__ bsum, int nb) {
  __shared__ int buf[256];
  int t = threadIdx.x;
  int v = (t < nb) ? bsum[t] : 0;
  buf[t] = v;
  __syncthreads();
  for (int off = 1; off < 256; off <<= 1) {
    int y = (t >= off) ? buf[t - off] : 0;
    __syncthreads();
    buf[t] += y;
    __syncthreads();
  }
  if (t < nb) bsum[t] = buf[t] - v;  // exclusive
}

__global__ __launch_bounds__(256) void scan3_kernel(
    int* __restrict__ arr, const int* __restrict__ bsum, int L) {
  int i = blockIdx.x * 256 + threadIdx.x;
  if (i < L) arr[i] += bsum[i >> 10];
}

// ---------------- A3: bucketize edges -> bdw[pos] = {w(32) | l(8) | src(20)}
__global__ __launch_bounds__(256) void a3_bucketize_kernel(
    const int* __restrict__ src, const int* __restrict__ dst,
    const float* __restrict__ w, const int* __restrict__ gtable,
    unsigned long long* __restrict__ bdw, int E, int NBA) {
  __shared__ unsigned int bh[392];
  int bid = blockIdx.x;
  int tid = threadIdx.x;
  for (int k = tid; k < 392; k += 256) bh[k] = 0u;
  __syncthreads();
  int e0 = bid * EBLK;
  #pragma unroll 4
  for (int it = 0; it < EBLK / 256; ++it) {
    int e = e0 + it * 256 + tid;
    if (e < E) {
      int d = dst[e];
      int k = d >> 8;
      unsigned int l = (unsigned int)(d & 255);
      unsigned int r = atomicAdd(&bh[k], 1u);
      int pos = gtable[k * NBA + bid] + (int)r;
      unsigned int lo = (unsigned int)src[e] | (l << 20);
      unsigned long long v = ((unsigned long long)__float_as_uint(w[e]) << 32)
                           | (unsigned long long)lo;
      bdw[pos] = v;
    }
  }
}

// ---------------- B1: per-bucket degree + rowptr + dinv (LDS atomics)
__global__ __launch_bounds__(256) void b1_degree_kernel(
    const unsigned long long* __restrict__ bdw,
    const int* __restrict__ gtable, int* __restrict__ rowptr,
    float* __restrict__ dinv, int E, int NBA, int NB, int N) {
  __shared__ unsigned int lcnt[256];
  __shared__ unsigned int lwfx[256];
  __shared__ int sc[256];
  int k = blockIdx.x;
  int t = threadIdx.x;
  lcnt[t] = 0u; lwfx[t] = 0u;
  __syncthreads();
  int base = gtable[k * NBA];
  int end  = (k + 1 < NB) ? gtable[(k + 1) * NBA] : E;
  for (int i = base + t; i < end; i += 256) {
    unsigned long long v = bdw[i];
    unsigned int lo = (unsigned int)v;
    unsigned int l = (lo >> 20) & 0xFFu;
    float wv = __uint_as_float((unsigned int)(v >> 32));
    atomicAdd(&lcnt[l], 1u);
    atomicAdd(&lwfx[l], (unsigned int)(wv * WFX));
  }
  __syncthreads();
  int c = (int)lcnt[t];
  sc[t] = c;
  __syncthreads();
  for (int off = 1; off < 256; off <<= 1) {
    int y = (t >= off) ? sc[t - off] : 0;
    __syncthreads();
    sc[t] += y;
    __syncthreads();
  }
  int excl = sc[t] - c;
  int node = (k << 8) + t;
  if (node < N) {
    rowptr[node] = base + excl;
    float deg = (float)lwfx[t] * WFXI;
    dinv[node] = rsqrtf(1.0f + deg);
  }
  if (k == 0 && t == 0) rowptr[N] = E;
}

// ---------------- B2: per-bucket CSR scatter: edges[rowptr[d]+rank]={src,norm}
__global__ __launch_bounds__(256) void b2_scatter_kernel(
    const unsigned long long* __restrict__ bdw,
    const int* __restrict__ gtable, const int* __restrict__ rowptr,
    const float* __restrict__ dinv, int2* __restrict__ edges,
    int E, int NBA, int NB) {
  __shared__ unsigned int rcnt[256];
  int k = blockIdx.x;
  int t = threadIdx.x;
  rcnt[t] = 0u;
  __syncthreads();
  int base = gtable[k * NBA];
  int end  = (k + 1 < NB) ? gtable[(k + 1) * NBA] : E;
  for (int i = base + t; i < end; i += 256) {
    unsigned long long v = bdw[i];
    unsigned int lo = (unsigned int)v;
    int s = (int)(lo & 0xFFFFFu);
    unsigned int l = (lo >> 20) & 0xFFu;
    float wv = __uint_as_float((unsigned int)(v >> 32));
    unsigned int r = atomicAdd(&rcnt[l], 1u);
    int d = (k << 8) + (int)l;
    int pos = rowptr[d] + (int)r;
    float nm = dinv[s] * wv * dinv[d];
    edges[pos] = make_int2(s, __float_as_int(nm));
  }
}

// ---------------- GEMM2: H2h[N,64](fp16) = A1h[N,128](fp16) @ W2[128,64]
__global__ __launch_bounds__(256) void gemm2_kernel(
    const unsigned short* __restrict__ A1h, const float* __restrict__ W2,
    unsigned short* __restrict__ H2h, int N) {
  __shared__ __align__(16) float xs[64][17];
  __shared__ __align__(16) float ws[16 * FO];
  int tid = threadIdx.x;
  int row0 = blockIdx.x * 64;
  int tx = tid & 15;        // cols tx*4..+3
  int ty = tid >> 4;        // rows ty*4..+3
  float acc[4][4];
  #pragma unroll
  for (int i = 0; i < 4; ++i)
    #pragma unroll
    for (int j = 0; j < 4; ++j) acc[i][j] = 0.f;

  for (int k0 = 0; k0 < FH; k0 += 16) {
    {
      int r = tid >> 2, kq = (tid & 3) * 4;
      int gr = row0 + r;
      uint2 v = make_uint2(0u, 0u);
      if (gr < N) v = *(const uint2*)(A1h + (size_t)gr * FH + k0 + kq);
      xs[r][kq + 0] = h2f(v.x & 0xffffu); xs[r][kq + 1] = h2f(v.x >> 16);
      xs[r][kq + 2] = h2f(v.y & 0xffffu); xs[r][kq + 3] = h2f(v.y >> 16);
    }
    {
      const float4* s4 = (const float4*)(W2 + (size_t)k0 * FO);
      float4* d4 = (float4*)ws;
      d4[tid] = s4[tid];
    }
    __syncthreads();
    #pragma unroll
    for (int kk = 0; kk < 16; ++kk) {
      float xv[4];
      #pragma unroll
      for (int i = 0; i < 4; ++i) xv[i] = xs[ty * 4 + i][kk];
      float4 wv = *(const float4*)(&ws[kk * FO + tx * 4]);
      #pragma unroll
      for (int i = 0; i < 4; ++i) {
        acc[i][0] += xv[i] * wv.x; acc[i][1] += xv[i] * wv.y;
        acc[i][2] += xv[i] * wv.z; acc[i][3] += xv[i] * wv.w;
      }
    }
    __syncthreads();
  }
  #pragma unroll
  for (int i = 0; i < 4; ++i) {
    int gr = row0 + ty * 4 + i;
    if (gr < N) {
      uint2 pk;
      pk.x = f2h(acc[i][0]) | (f2h(acc[i][1]) << 16);
      pk.y = f2h(acc[i][2]) | (f2h(acc[i][3]) << 16);
      *(uint2*)(H2h + (size_t)gr * FO + tx * 4) = pk;
    }
  }
}

// ---------------- agg1: a1h = relu(A @ h1 + b1), 128 fp16 feats
// quarter-wave per row: 16 lanes x 16B; 4 edges/wave x2 unroll = 8 in flight
__global__ __launch_bounds__(256) void agg1_kernel(
    const unsigned short* __restrict__ H1h, const int2* __restrict__ edges,
    const int* __restrict__ rowptr, const float* __restrict__ dinv,
    const float* __restrict__ b1, unsigned short* __restrict__ A1h, int N) {
  int wid = (blockIdx.x * 256 + threadIdx.x) >> 6;
  int lane = threadIdx.x & 63;
  if (wid >= N) return;
  int p0 = rowptr[wid], p1 = rowptr[wid + 1];
  int grp = lane >> 4, li = lane & 15;      // li covers feats li*8..+7
  const size_t rowoff = (size_t)li * 8;
  float a0[8], a1[8];
  #pragma unroll
  for (int j = 0; j < 8; ++j) { a0[j] = 0.f; a1[j] = 0.f; }

  int p = p0;
  for (; p + 8 <= p1; p += 8) {
    int2 e0 = edges[p + grp];
    int2 e1 = edges[p + 4 + grp];
    uint4 h0 = *(const uint4*)(H1h + (size_t)e0.x * FH + rowoff);
    uint4 h1 = *(const uint4*)(H1h + (size_t)e1.x * FH + rowoff);
    float n0 = __int_as_float(e0.y), n1 = __int_as_float(e1.y);
    a0[0] += n0 * h2f(h0.x & 0xffffu); a0[1] += n0 * h2f(h0.x >> 16);
    a0[2] += n0 * h2f(h0.y & 0xffffu); a0[3] += n0 * h2f(h0.y >> 16);
    a0[4] += n0 * h2f(h0.z & 0xffffu); a0[5] += n0 * h2f(h0.z >> 16);
    a0[6] += n0 * h2f(h0.w & 0xffffu); a0[7] += n0 * h2f(h0.w >> 16);
    a1[0] += n1 * h2f(h1.x & 0xffffu); a1[1] += n1 * h2f(h1.x >> 16);
    a1[2] += n1 * h2f(h1.y & 0xffffu); a1[3] += n1 * h2f(h1.y >> 16);
    a1[4] += n1 * h2f(h1.z & 0xffffu); a1[5] += n1 * h2f(h1.z >> 16);
    a1[6] += n1 * h2f(h1.w & 0xffffu); a1[7] += n1 * h2f(h1.w >> 16);
  }
  for (; p + 4 <= p1; p += 4) {
    int2 e0 = edges[p + grp];
    uint4 h0 = *(const uint4*)(H1h + (size_t)e0.x * FH + rowoff);
    float n0 = __int_as_float(e0.y);
    a0[0] += n0 * h2f(h0.x & 0xffffu); a0[1] += n0 * h2f(h0.x >> 16);
    a0[2] += n0 * h2f(h0.y & 0xffffu); a0[3] += n0 * h2f(h0.y >> 16);
    a0[4] += n0 * h2f(h0.z & 0xffffu); a0[5] += n0 * h2f(h0.z >> 16);
    a0[6] += n0 * h2f(h0.w & 0xffffu); a0[7] += n0 * h2f(h0.w >> 16);
  }
  if (p < p1) {  // 1..3 leftover edges: masked
    int q = p + grp;
    int qi = (q < p1) ? q : p;
    int2 e0 = edges[qi];
    float n0 = (q < p1) ? __int_as_float(e0.y) : 0.f;
    uint4 h0 = *(const uint4*)(H1h + (size_t)e0.x * FH + rowoff);
    a0[0] += n0 * h2f(h0.x & 0xffffu); a0[1] += n0 * h2f(h0.x >> 16);
    a0[2] += n0 * h2f(h0.y & 0xffffu); a0[3] += n0 * h2f(h0.y >> 16);
    a0[4] += n0 * h2f(h0.z & 0xffffu); a0[5] += n0 * h2f(h0.z >> 16);
    a0[6] += n0 * h2f(h0.w & 0xffffu); a0[7] += n0 * h2f(h0.w >> 16);
  }
  float s[8];
  #pragma unroll
  for (int j = 0; j < 8; ++j) {
    s[j] = a0[j] + a1[j];
    s[j] += __shfl_xor(s[j], 16);
    s[j] += __shfl_xor(s[j], 32);
  }
  if (lane < 16) {
    float di = dinv[wid], sn = di * di;
    uint4 hs = *(const uint4*)(H1h + (size_t)wid * FH + rowoff);
    s[0] += sn * h2f(hs.x & 0xffffu); s[1] += sn * h2f(hs.x >> 16);
    s[2] += sn * h2f(hs.y & 0xffffu); s[3] += sn * h2f(hs.y >> 16);
    s[4] += sn * h2f(hs.z & 0xffffu); s[5] += sn * h2f(hs.z >> 16);
    s[6] += sn * h2f(hs.w & 0xffffu); s[7] += sn * h2f(hs.w >> 16);
    float4 bv0 = *(const float4*)(b1 + li * 8);
    float4 bv1 = *(const float4*)(b1 + li * 8 + 4);
    s[0] = fmaxf(s[0] + bv0.x, 0.f); s[1] = fmaxf(s[1] + bv0.y, 0.f);
    s[2] = fmaxf(s[2] + bv0.z, 0.f); s[3] = fmaxf(s[3] + bv0.w, 0.f);
    s[4] = fmaxf(s[4] + bv1.x, 0.f); s[5] = fmaxf(s[5] + bv1.y, 0.f);
    s[6] = fmaxf(s[6] + bv1.z, 0.f); s[7] = fmaxf(s[7] + bv1.w, 0.f);
    uint4 pk;
    pk.x = f2h(s[0]) | (f2h(s[1]) << 16);
    pk.y = f2h(s[2]) | (f2h(s[3]) << 16);
    pk.z = f2h(s[4]) | (f2h(s[5]) << 16);
    pk.w = f2h(s[6]) | (f2h(s[7]) << 16);
    *(uint4*)(A1h + (size_t)wid * FH + li * 8) = pk;
  }
}

// ---------------- agg2: out = A @ h2 + b2, 64 fp16 feats
// eighth-wave per row: 8 lanes x 16B; 8 edges/wave x2 unroll = 16 in flight
__global__ __launch_bounds__(256) void agg2_kernel(
    const unsigned short* __restrict__ H2h, const int2* __restrict__ edges,
    const int* __restrict__ rowptr, const float* __restrict__ dinv,
    const float* __restrict__ b2, float* __restrict__ OUT, int N) {
  int wid = (blockIdx.x * 256 + threadIdx.x) >> 6;
  int lane = threadIdx.x & 63;
  if (wid >= N) return;
  int p0 = rowptr[wid], p1 = rowptr[wid + 1];
  int grp = lane >> 3, li = lane & 7;       // li covers feats li*8..+7
  const size_t rowoff = (size_t)li * 8;
  float a0[8], a1[8];
  #pragma unroll
  for (int j = 0; j < 8; ++j) { a0[j] = 0.f; a1[j] = 0.f; }

  int p = p0;
  for (; p + 16 <= p1; p += 16) {
    int2 e0 = edges[p + grp];
    int2 e1 = edges[p + 8 + grp];
    uint4 h0 = *(const uint4*)(H2h + (size_t)e0.x * FO + rowoff);
    uint4 h1 = *(const uint4*)(H2h + (size_t)e1.x * FO + rowoff);
    float n0 = __int_as_float(e0.y), n1 = __int_as_float(e1.y);
    a0[0] += n0 * h2f(h0.x & 0xffffu); a0[1] += n0 * h2f(h0.x >> 16);
    a0[2] += n0 * h2f(h0.y & 0xffffu); a0[3] += n0 * h2f(h0.y >> 16);
    a0[4] += n0 * h2f(h0.z & 0xffffu); a0[5] += n0 * h2f(h0.z >> 16);
    a0[6] += n0 * h2f(h0.w & 0xffffu); a0[7] += n0 * h2f(h0.w >> 16);
    a1[0] += n1 * h2f(h1.x & 0xffffu); a1[1] += n1 * h2f(h1.x >> 16);
    a1[2] += n1 * h2f(h1.y & 0xffffu); a1[3] += n1 * h2f(h1.y >> 16);
    a1[4] += n1 * h2f(h1.z & 0xffffu); a1[5] += n1 * h2f(h1.z >> 16);
    a1[6] += n1 * h2f(h1.w & 0xffffu); a1[7] += n1 * h2f(h1.w >> 16);
  }
  for (; p + 8 <= p1; p += 8) {
    int2 e0 = edges[p + grp];
    uint4 h0 = *(const uint4*)(H2h + (size_t)e0.x * FO + rowoff);
    float n0 = __int_as_float(e0.y);
    a0[0] += n0 * h2f(h0.x & 0xffffu); a0[1] += n0 * h2f(h0.x >> 16);
    a0[2] += n0 * h2f(h0.y & 0xffffu); a0[3] += n0 * h2f(h0.y >> 16);
    a0[4] += n0 * h2f(h0.z & 0xffffu); a0[5] += n0 * h2f(h0.z >> 16);
    a0[6] += n0 * h2f(h0.w & 0xffffu); a0[7] += n0 * h2f(h0.w >> 16);
  }
  if (p < p1) {  // 1..7 leftover edges: masked
    int q = p + grp;
    int qi = (q < p1) ? q : p;
    int2 e0 = edges[qi];
    float n0 = (q < p1) ? __int_as_float(e0.y) : 0.f;
    uint4 h0 = *(const uint4*)(H2h + (size_t)e0.x * FO + rowoff);
    a0[0] += n0 * h2f(h0.x & 0xffffu); a0[1] += n0 * h2f(h0.x >> 16);
    a0[2] += n0 * h2f(h0.y & 0xffffu); a0[3] += n0 * h2f(h0.y >> 16);
    a0[4] += n0 * h2f(h0.z & 0xffffu); a0[5] += n0 * h2f(h0.z >> 16);
    a0[6] += n0 * h2f(h0.w & 0xffffu); a0[7] += n0 * h2f(h0.w >> 16);
  }
  float s[8];
  #pragma unroll
  for (int j = 0; j < 8; ++j) {
    s[j] = a0[j] + a1[j];
    s[j] += __shfl_xor(s[j], 8);
    s[j] += __shfl_xor(s[j], 16);
    s[j] += __shfl_xor(s[j], 32);
  }
  if (lane < 8) {
    float di = dinv[wid], sn = di * di;
    uint4 hs = *(const uint4*)(H2h + (size_t)wid * FO + rowoff);
    s[0] += sn * h2f(hs.x & 0xffffu); s[1] += sn * h2f(hs.x >> 16);
    s[2] += sn * h2f(hs.y & 0xffffu); s[3] += sn * h2f(hs.y >> 16);
    s[4] += sn * h2f(hs.z & 0xffffu); s[5] += sn * h2f(hs.z >> 16);
    s[6] += sn * h2f(hs.w & 0xffffu); s[7] += sn * h2f(hs.w >> 16);
    float4 bv0 = *(const float4*)(b2 + li * 8);
    float4 bv1 = *(const float4*)(b2 + li * 8 + 4);
    float4 o0 = make_float4(s[0] + bv0.x, s[1] + bv0.y, s[2] + bv0.z, s[3] + bv0.w);
    float4 o1 = make_float4(s[4] + bv1.x, s[5] + bv1.y, s[6] + bv1.z, s[7] + bv1.w);
    *(float4*)(OUT + (size_t)wid * FO + li * 8) = o0;
    *(float4*)(OUT + (size_t)wid * FO + li * 8 + 4) = o1;
  }
}

extern "C" void kernel_launch(void* const* d_in, const int* in_sizes, int n_in,
                              void* d_out, int out_size, void* d_ws, size_t ws_size,
                              hipStream_t stream) {
  const float* x  = (const float*)d_in[0];
  const int*   ei = (const int*)d_in[1];
  const float* ew = (const float*)d_in[2];
  const float* W1 = (const float*)d_in[3];
  const float* b1 = (const float*)d_in[4];
  const float* W2 = (const float*)d_in[5];
  const float* b2 = (const float*)d_in[6];
  float* out = (float*)d_out;

  const int N = in_sizes[0] / FIN;        // 100000
  const int E = in_sizes[2];              // 3200000
  const int* src = ei;
  const int* dst = ei + E;
  const int NBG = (N + 63) / 64;          // gemm1 tiles (1563)
  const int NBA = (E + EBLK - 1) / EBLK;  // A-phase blocks (391)
  const int NB  = (N + 255) / 256;        // buckets (391)
  const int L   = NB * NBA;               // gtable length (152,881)
  const int nsb = (L + 1023) / 1024;      // scan blocks (150, <=256)

  // workspace layout (16B-aligned slices), ~117MB total
  char* ws = (char*)d_ws;
  size_t off = 0;
  unsigned short* h1h = (unsigned short*)(ws + off); off += (size_t)N * FH * 2;  // fp16 h1
  unsigned short* h2h = (unsigned short*)(ws + off); off += (size_t)N * FO * 2;  // fp16 h2
  unsigned short* a1h = (unsigned short*)(ws + off); off += (size_t)N * FH * 2;  // fp16 a1
  int2*  edges  = (int2*) (ws + off); off += (size_t)E * 8;
  unsigned long long* bdw = (unsigned long long*)(ws + off); off += (size_t)E * 8;
  int*   gtable = (int*)  (ws + off); off += (((size_t)L * 4) + 15) & ~(size_t)15;
  int*   rowptr = (int*)  (ws + off); off += (((size_t)(N + 1) * 4) + 15) & ~(size_t)15;
  float* dinv   = (float*)(ws + off); off += (size_t)N * 4;
  int*   bsum   = (int*)  (ws + off); off += 1024;

  // CSR build (LDS-atomic bucketed) + gemm1 fused into A1
  a1hist_gemm1_kernel<<<NBA + NBG, 256, 0, stream>>>(dst, gtable, E, NBA, NB,
                                                     x, W1, h1h, N, NBG);
  scan1i_kernel<<<nsb, 256, 0, stream>>>(gtable, bsum, L);
  scan2_kernel<<<1, 256, 0, stream>>>(bsum, nsb);
  scan3_kernel<<<(L + 255) / 256, 256, 0, stream>>>(gtable, bsum, L);
  a3_bucketize_kernel<<<NBA, 256, 0, stream>>>(src, dst, ew, gtable, bdw, E, NBA);
  b1_degree_kernel<<<NB, 256, 0, stream>>>(bdw, gtable, rowptr, dinv, E, NBA, NB, N);
  b2_scatter_kernel<<<NB, 256, 0, stream>>>(bdw, gtable, rowptr, dinv, edges,
                                            E, NBA, NB);
  // layers
  agg1_kernel<<<(N * 64 + 255) / 256, 256, 0, stream>>>(h1h, edges, rowptr,
                                                        dinv, b1, a1h, N);
  gemm2_kernel<<<(N + 63) / 64, 256, 0, stream>>>(a1h, W2, h2h, N);
  agg2_kernel<<<(N * 64 + 255) / 256, 256, 0, stream>>>(h2h, edges, rowptr,
                                                        dinv, b2, out, N);
}

// Round 12
// 371.450 us; speedup vs baseline: 1.3655x; 1.2126x over previous
//
#include <hip/hip_runtime.h>
#include <hip/hip_bf16.h>

// GCN 2-layer encoder: N=100000 nodes, E=3.2M edges, Fin=256, Fh=128, Fo=64.
//   h1 = x@W1 ; a1 = relu(A@h1 + b1) ; h2 = a1@W2 ; out = A@h2 + b2
//
// R12: both GEMMs moved to MFMA (mfma_f32_16x16x32_bf16). R11 showed the
// f32 vector gemm1 as the long pole (VALUBusy 50%, MfmaUtil 0) inside the
// fused build kernel. W1/W2 pre-transposed to bf16 (WT1[128][256],
// WT2[64][128]); x / a1 converted to bf16 at staging (error ~1-3e-4 at
// output; margin 1.95e-3 vs 8.28e-3). Fragment layout (guide m89):
//   A[l&15][(l>>4)*8+b] ; B[(l>>4)*8+b][l&15] ; D row=(l>>4)*4+r col=l&15
// LDS tiles use 40-short row stride (80B -> 2-way bank alias, free).
// a1 stored bf16 (feeds only gemm2); h1/h2 stay fp16 for the agg gathers.
// CSR build (R11 LDS-atomic bucketed) and agg kernels unchanged.

#define FIN 256
#define FH  128
#define FO  64

#define EBLK 8192                     // edges per A-phase block (256 thr x 32)
#define WFX  33554432.0f              // 2^25 fixed-point degree scale
#define WFXI (1.0f / 33554432.0f)

typedef short s16x8 __attribute__((ext_vector_type(8)));
typedef float f32x4 __attribute__((ext_vector_type(4)));

__device__ __forceinline__ float h2f(unsigned int u16) {
  union { unsigned short s; _Float16 h; } c; c.s = (unsigned short)u16;
  return (float)c.h;
}
__device__ __forceinline__ unsigned int f2h(float f) {
  union { _Float16 h; unsigned short s; } c; c.h = (_Float16)f;  // RNE cvt
  return (unsigned int)c.s;
}
__device__ __forceinline__ unsigned int f2bf(float f) {
  union { float f; unsigned int i; } c; c.f = f;
  unsigned int i = c.i;
  return (i + 0x7FFFu + ((i >> 16) & 1u)) >> 16;  // RNE
}

// ---------------- prep: WT1[j][k]=bf16(W1[k][j]); WT2[j][k]=bf16(W2[k][j])
__global__ __launch_bounds__(256) void prep_w_kernel(
    const float* __restrict__ W1, const float* __restrict__ W2,
    unsigned short* __restrict__ WT1, unsigned short* __restrict__ WT2) {
  int i = blockIdx.x * 256 + threadIdx.x;
  if (i < FIN * FH) {
    int k = i >> 7, j = i & 127;
    WT1[j * FIN + k] = (unsigned short)f2bf(W1[i]);
  } else {
    int i2 = i - FIN * FH;
    if (i2 < FH * FO) {
      int k = i2 >> 6, j = i2 & 63;
      WT2[j * FH + k] = (unsigned short)f2bf(W2[i2]);
    }
  }
}

// ---------------- A1 hist (blocks [0,NBA)) + MFMA gemm1 (blocks [NBA,..))
__global__ __launch_bounds__(256) void a1hist_gemm1_kernel(
    const int* __restrict__ dst, int* __restrict__ gtable, int E,
    int NBA, int NB,
    const float* __restrict__ X, const unsigned short* __restrict__ WT1,
    unsigned short* __restrict__ H1h, int N, int NBG) {
  __shared__ __align__(16) short XS[64 * 40];    // 64 rows x 32 k (bf16)
  __shared__ __align__(16) short WTS[128 * 40];  // 128 cols x 32 k (bf16)
  __shared__ unsigned int bh[392];
  int bid = blockIdx.x;
  int tid = threadIdx.x;
  if (bid < NBA) {
    // ---- bucket-histogram role
    for (int k = tid; k < NB; k += 256) bh[k] = 0u;
    __syncthreads();
    int e0 = bid * EBLK;
    #pragma unroll 4
    for (int it = 0; it < EBLK / 256; ++it) {
      int e = e0 + it * 256 + tid;
      if (e < E) atomicAdd(&bh[dst[e] >> 8], 1u);
    }
    __syncthreads();
    for (int k = tid; k < NB; k += 256)
      gtable[k * NBA + bid] = (int)bh[k];
    return;
  }
  int g = bid - NBA;
  if (g >= NBG) return;
  // ---- MFMA gemm1 role: H1h[64 rows,128 cols] fp16 = X @ W1 (bf16 MFMA)
  int row0 = g * 64;
  int wave = tid >> 6, lane = tid & 63;
  int lr = lane & 15, lq = lane >> 4;          // fragment row/col & k-octet
  f32x4 acc[8];
  #pragma unroll
  for (int c = 0; c < 8; ++c) acc[c] = (f32x4)(0.f);

  for (int k0 = 0; k0 < FIN; k0 += 32) {
    {  // stage XS: thread t -> row t>>2, koff (t&3)*8 ; f32 -> bf16
      int row = tid >> 2, koff = (tid & 3) * 8;
      int gr = row0 + row;
      float4 va = make_float4(0.f, 0.f, 0.f, 0.f), vb = va;
      if (gr < N) {
        va = *(const float4*)(X + (size_t)gr * FIN + k0 + koff);
        vb = *(const float4*)(X + (size_t)gr * FIN + k0 + koff + 4);
      }
      s16x8 hv;
      hv[0] = (short)f2bf(va.x); hv[1] = (short)f2bf(va.y);
      hv[2] = (short)f2bf(va.z); hv[3] = (short)f2bf(va.w);
      hv[4] = (short)f2bf(vb.x); hv[5] = (short)f2bf(vb.y);
      hv[6] = (short)f2bf(vb.z); hv[7] = (short)f2bf(vb.w);
      *(s16x8*)(&XS[row * 40 + koff]) = hv;
    }
    {  // stage WTS: thread t -> j t>>1, 16-half o (t&1)*16 (WT1 is bf16)
      int j = tid >> 1, o = (tid & 1) * 16;
      uint4 v0 = *(const uint4*)(WT1 + (size_t)j * FIN + k0 + o);
      uint4 v1 = *(const uint4*)(WT1 + (size_t)j * FIN + k0 + o + 8);
      *(uint4*)(&WTS[j * 40 + o]) = v0;
      *(uint4*)(&WTS[j * 40 + o + 8]) = v1;
    }
    __syncthreads();
    s16x8 af = *(const s16x8*)(&XS[(wave * 16 + lr) * 40 + lq * 8]);
    #pragma unroll
    for (int c = 0; c < 8; ++c) {
      s16x8 bf = *(const s16x8*)(&WTS[(c * 16 + lr) * 40 + lq * 8]);
      acc[c] = __builtin_amdgcn_mfma_f32_16x16x32_bf16(af, bf, acc[c], 0, 0, 0);
    }
    __syncthreads();
  }
  // epilogue: D row=(l>>4)*4+r (within wave's 16), col=c*16+(l&15)
  int orow = row0 + wave * 16 + lq * 4;
  #pragma unroll
  for (int c = 0; c < 8; ++c) {
    #pragma unroll
    for (int r = 0; r < 4; ++r) {
      int gr = orow + r;
      if (gr < N)
        H1h[(size_t)gr * FH + c * 16 + lr] = (unsigned short)f2h(acc[c][r]);
    }
  }
}

// ---------------- 3-phase exclusive scan, in-place on int array of length L
__global__ __launch_bounds__(256) void scan1i_kernel(
    int* __restrict__ arr, int* __restrict__ bsum, int L) {
  __shared__ int tot[256];
  int t = threadIdx.x;
  int base = blockIdx.x * 1024 + t * 4;
  int v0 = (base + 0 < L) ? arr[base + 0] : 0;
  int v1 = (base + 1 < L) ? arr[base + 1] : 0;
  int v2 = (base + 2 < L) ? arr[base + 2] : 0;
  int v3 = (base + 3 < L) ? arr[base + 3] : 0;
  int s = v0 + v1 + v2 + v3;
  tot[t] = s;
  __syncthreads();
  for (int off = 1; off < 256; off <<= 1) {
    int y = (t >= off) ? tot[t - off] : 0;
    __syncthreads();
    tot[t] += y;
    __syncthreads();
  }
  int p = tot[t] - s;  // exclusive within block
  if (t == 255) bsum[blockIdx.x] = tot[255];
  if (base + 0 < L) arr[base + 0] = p; p += v0;
  if (base + 1 < L) arr[base + 1] = p; p += v1;
  if (base + 2 < L) arr[base + 2] = p; p += v2;
  if (base + 3 < L) arr[base + 3] = p;
}

__global__ __launch_bounds__(256) void scan2_kernel(
    int* __restrict__ bsum, int nb) {
  __shared__ int buf[256];
  int t = threadIdx.x;
  int v = (t < nb) ? bsum[t] : 0;
  buf[t] = v;
  __syncthreads();
  for (int off = 1; off < 256; off <<= 1) {
    int y = (t >= off) ? buf[t - off] : 0;
    __syncthreads();
    buf[t] += y;
    __syncthreads();
  }
  if (t < nb) bsum[t] = buf[t] - v;  // exclusive
}

__global__ __launch_bounds__(256) void scan3_kernel(
    int* __restrict__ arr, const int* __restrict__ bsum, int L) {
  int i = blockIdx.x * 256 + threadIdx.x;
  if (i < L) arr[i] += bsum[i >> 10];
}

// ---------------- A3: bucketize edges -> bdw[pos] = {w(32) | l(8) | src(20)}
__global__ __launch_bounds__(256) void a3_bucketize_kernel(
    const int* __restrict__ src, const int* __restrict__ dst,
    const float* __restrict__ w, const int* __restrict__ gtable,
    unsigned long long* __restrict__ bdw, int E, int NBA) {
  __shared__ unsigned int bh[392];
  int bid = blockIdx.x;
  int tid = threadIdx.x;
  for (int k = tid; k < 392; k += 256) bh[k] = 0u;
  __syncthreads();
  int e0 = bid * EBLK;
  #pragma unroll 4
  for (int it = 0; it < EBLK / 256; ++it) {
    int e = e0 + it * 256 + tid;
    if (e < E) {
      int d = dst[e];
      int k = d >> 8;
      unsigned int l = (unsigned int)(d & 255);
      unsigned int r = atomicAdd(&bh[k], 1u);
      int pos = gtable[k * NBA + bid] + (int)r;
      unsigned int lo = (unsigned int)src[e] | (l << 20);
      unsigned long long v = ((unsigned long long)__float_as_uint(w[e]) << 32)
                           | (unsigned long long)lo;
      bdw[pos] = v;
    }
  }
}

// ---------------- B1: per-bucket degree + rowptr + dinv (LDS atomics)
__global__ __launch_bounds__(256) void b1_degree_kernel(
    const unsigned long long* __restrict__ bdw,
    const int* __restrict__ gtable, int* __restrict__ rowptr,
    float* __restrict__ dinv, int E, int NBA, int NB, int N) {
  __shared__ unsigned int lcnt[256];
  __shared__ unsigned int lwfx[256];
  __shared__ int sc[256];
  int k = blockIdx.x;
  int t = threadIdx.x;
  lcnt[t] = 0u; lwfx[t] = 0u;
  __syncthreads();
  int base = gtable[k * NBA];
  int end  = (k + 1 < NB) ? gtable[(k + 1) * NBA] : E;
  for (int i = base + t; i < end; i += 256) {
    unsigned long long v = bdw[i];
    unsigned int lo = (unsigned int)v;
    unsigned int l = (lo >> 20) & 0xFFu;
    float wv = __uint_as_float((unsigned int)(v >> 32));
    atomicAdd(&lcnt[l], 1u);
    atomicAdd(&lwfx[l], (unsigned int)(wv * WFX));
  }
  __syncthreads();
  int c = (int)lcnt[t];
  sc[t] = c;
  __syncthreads();
  for (int off = 1; off < 256; off <<= 1) {
    int y = (t >= off) ? sc[t - off] : 0;
    __syncthreads();
    sc[t] += y;
    __syncthreads();
  }
  int excl = sc[t] - c;
  int node = (k << 8) + t;
  if (node < N) {
    rowptr[node] = base + excl;
    float deg = (float)lwfx[t] * WFXI;
    dinv[node] = rsqrtf(1.0f + deg);
  }
  if (k == 0 && t == 0) rowptr[N] = E;
}

// ---------------- B2: per-bucket CSR scatter: edges[rowptr[d]+rank]={src,norm}
__global__ __launch_bounds__(256) void b2_scatter_kernel(
    const unsigned long long* __restrict__ bdw,
    const int* __restrict__ gtable, const int* __restrict__ rowptr,
    const float* __restrict__ dinv, int2* __restrict__ edges,
    int E, int NBA, int NB) {
  __shared__ unsigned int rcnt[256];
  int k = blockIdx.x;
  int t = threadIdx.x;
  rcnt[t] = 0u;
  __syncthreads();
  int base = gtable[k * NBA];
  int end  = (k + 1 < NB) ? gtable[(k + 1) * NBA] : E;
  for (int i = base + t; i < end; i += 256) {
    unsigned long long v = bdw[i];
    unsigned int lo = (unsigned int)v;
    int s = (int)(lo & 0xFFFFFu);
    unsigned int l = (lo >> 20) & 0xFFu;
    float wv = __uint_as_float((unsigned int)(v >> 32));
    unsigned int r = atomicAdd(&rcnt[l], 1u);
    int d = (k << 8) + (int)l;
    int pos = rowptr[d] + (int)r;
    float nm = dinv[s] * wv * dinv[d];
    edges[pos] = make_int2(s, __float_as_int(nm));
  }
}

// ---------------- MFMA GEMM2: H2h[N,64] fp16 = A1b[N,128] bf16 @ W2
__global__ __launch_bounds__(256) void gemm2_kernel(
    const unsigned short* __restrict__ A1b, const unsigned short* __restrict__ WT2,
    unsigned short* __restrict__ H2h, int N) {
  __shared__ __align__(16) short XS[64 * 40];   // 64 rows x 32 k
  __shared__ __align__(16) short WTS[64 * 40];  // 64 cols x 32 k
  int tid = threadIdx.x;
  int row0 = blockIdx.x * 64;
  int wave = tid >> 6, lane = tid & 63;
  int lr = lane & 15, lq = lane >> 4;
  f32x4 acc[4];
  #pragma unroll
  for (int c = 0; c < 4; ++c) acc[c] = (f32x4)(0.f);

  for (int k0 = 0; k0 < FH; k0 += 32) {
    {  // stage XS: row=t>>2, o=(t&3)*8 (A1b already bf16)
      int row = tid >> 2, o = (tid & 3) * 8;
      int gr = row0 + row;
      uint4 v = make_uint4(0u, 0u, 0u, 0u);
      if (gr < N) v = *(const uint4*)(A1b + (size_t)gr * FH + k0 + o);
      *(uint4*)(&XS[row * 40 + o]) = v;
    }
    {  // stage WTS: j=t>>2, o=(t&3)*8
      int j = tid >> 2, o = (tid & 3) * 8;
      uint4 v = *(const uint4*)(WT2 + (size_t)j * FH + k0 + o);
      *(uint4*)(&WTS[j * 40 + o]) = v;
    }
    __syncthreads();
    s16x8 af = *(const s16x8*)(&XS[(wave * 16 + lr) * 40 + lq * 8]);
    #pragma unroll
    for (int c = 0; c < 4; ++c) {
      s16x8 bf = *(const s16x8*)(&WTS[(c * 16 + lr) * 40 + lq * 8]);
      acc[c] = __builtin_amdgcn_mfma_f32_16x16x32_bf16(af, bf, acc[c], 0, 0, 0);
    }
    __syncthreads();
  }
  int orow = row0 + wave * 16 + lq * 4;
  #pragma unroll
  for (int c = 0; c < 4; ++c) {
    #pragma unroll
    for (int r = 0; r < 4; ++r) {
      int gr = orow + r;
      if (gr < N)
        H2h[(size_t)gr * FO + c * 16 + lr] = (unsigned short)f2h(acc[c][r]);
    }
  }
}

// ---------------- agg1: a1b = relu(A @ h1 + b1), out bf16 (feeds MFMA gemm2)
// quarter-wave per row: 16 lanes x 16B; 4 edges/wave x2 unroll = 8 in flight
__global__ __launch_bounds__(256) void agg1_kernel(
    const unsigned short* __restrict__ H1h, const int2* __restrict__ edges,
    const int* __restrict__ rowptr, const float* __restrict__ dinv,
    const float* __restrict__ b1, unsigned short* __restrict__ A1b, int N) {
  int wid = (blockIdx.x * 256 + threadIdx.x) >> 6;
  int lane = threadIdx.x & 63;
  if (wid >= N) return;
  int p0 = rowptr[wid], p1 = rowptr[wid + 1];
  int grp = lane >> 4, li = lane & 15;      // li covers feats li*8..+7
  const size_t rowoff = (size_t)li * 8;
  float a0[8], a1[8];
  #pragma unroll
  for (int j = 0; j < 8; ++j) { a0[j] = 0.f; a1[j] = 0.f; }

  int p = p0;
  for (; p + 8 <= p1; p += 8) {
    int2 e0 = edges[p + grp];
    int2 e1 = edges[p + 4 + grp];
    uint4 h0 = *(const uint4*)(H1h + (size_t)e0.x * FH + rowoff);
    uint4 h1 = *(const uint4*)(H1h + (size_t)e1.x * FH + rowoff);
    float n0 = __int_as_float(e0.y), n1 = __int_as_float(e1.y);
    a0[0] += n0 * h2f(h0.x & 0xffffu); a0[1] += n0 * h2f(h0.x >> 16);
    a0[2] += n0 * h2f(h0.y & 0xffffu); a0[3] += n0 * h2f(h0.y >> 16);
    a0[4] += n0 * h2f(h0.z & 0xffffu); a0[5] += n0 * h2f(h0.z >> 16);
    a0[6] += n0 * h2f(h0.w & 0xffffu); a0[7] += n0 * h2f(h0.w >> 16);
    a1[0] += n1 * h2f(h1.x & 0xffffu); a1[1] += n1 * h2f(h1.x >> 16);
    a1[2] += n1 * h2f(h1.y & 0xffffu); a1[3] += n1 * h2f(h1.y >> 16);
    a1[4] += n1 * h2f(h1.z & 0xffffu); a1[5] += n1 * h2f(h1.z >> 16);
    a1[6] += n1 * h2f(h1.w & 0xffffu); a1[7] += n1 * h2f(h1.w >> 16);
  }
  for (; p + 4 <= p1; p += 4) {
    int2 e0 = edges[p + grp];
    uint4 h0 = *(const uint4*)(H1h + (size_t)e0.x * FH + rowoff);
    float n0 = __int_as_float(e0.y);
    a0[0] += n0 * h2f(h0.x & 0xffffu); a0[1] += n0 * h2f(h0.x >> 16);
    a0[2] += n0 * h2f(h0.y & 0xffffu); a0[3] += n0 * h2f(h0.y >> 16);
    a0[4] += n0 * h2f(h0.z & 0xffffu); a0[5] += n0 * h2f(h0.z >> 16);
    a0[6] += n0 * h2f(h0.w & 0xffffu); a0[7] += n0 * h2f(h0.w >> 16);
  }
  if (p < p1) {  // 1..3 leftover edges: masked
    int q = p + grp;
    int qi = (q < p1) ? q : p;
    int2 e0 = edges[qi];
    float n0 = (q < p1) ? __int_as_float(e0.y) : 0.f;
    uint4 h0 = *(const uint4*)(H1h + (size_t)e0.x * FH + rowoff);
    a0[0] += n0 * h2f(h0.x & 0xffffu); a0[1] += n0 * h2f(h0.x >> 16);
    a0[2] += n0 * h2f(h0.y & 0xffffu); a0[3] += n0 * h2f(h0.y >> 16);
    a0[4] += n0 * h2f(h0.z & 0xffffu); a0[5] += n0 * h2f(h0.z >> 16);
    a0[6] += n0 * h2f(h0.w & 0xffffu); a0[7] += n0 * h2f(h0.w >> 16);
  }
  float s[8];
  #pragma unroll
  for (int j = 0; j < 8; ++j) {
    s[j] = a0[j] + a1[j];
    s[j] += __shfl_xor(s[j], 16);
    s[j] += __shfl_xor(s[j], 32);
  }
  if (lane < 16) {
    float di = dinv[wid], sn = di * di;
    uint4 hs = *(const uint4*)(H1h + (size_t)wid * FH + rowoff);
    s[0] += sn * h2f(hs.x & 0xffffu); s[1] += sn * h2f(hs.x >> 16);
    s[2] += sn * h2f(hs.y & 0xffffu); s[3] += sn * h2f(hs.y >> 16);
    s[4] += sn * h2f(hs.z & 0xffffu); s[5] += sn * h2f(hs.z >> 16);
    s[6] += sn * h2f(hs.w & 0xffffu); s[7] += sn * h2f(hs.w >> 16);
    float4 bv0 = *(const float4*)(b1 + li * 8);
    float4 bv1 = *(const float4*)(b1 + li * 8 + 4);
    s[0] = fmaxf(s[0] + bv0.x, 0.f); s[1] = fmaxf(s[1] + bv0.y, 0.f);
    s[2] = fmaxf(s[2] + bv0.z, 0.f); s[3] = fmaxf(s[3] + bv0.w, 0.f);
    s[4] = fmaxf(s[4] + bv1.x, 0.f); s[5] = fmaxf(s[5] + bv1.y, 0.f);
    s[6] = fmaxf(s[6] + bv1.z, 0.f); s[7] = fmaxf(s[7] + bv1.w, 0.f);
    uint4 pk;
    pk.x = f2bf(s[0]) | (f2bf(s[1]) << 16);
    pk.y = f2bf(s[2]) | (f2bf(s[3]) << 16);
    pk.z = f2bf(s[4]) | (f2bf(s[5]) << 16);
    pk.w = f2bf(s[6]) | (f2bf(s[7]) << 16);
    *(uint4*)(A1b + (size_t)wid * FH + li * 8) = pk;
  }
}

// ---------------- agg2: out = A @ h2 + b2, 64 fp16 feats
// eighth-wave per row: 8 lanes x 16B; 8 edges/wave x2 unroll = 16 in flight
__global__ __launch_bounds__(256) void agg2_kernel(
    const unsigned short* __restrict__ H2h, const int2* __restrict__ edges,
    const int* __restrict__ rowptr, const float* __restrict__ dinv,
    const float* __restrict__ b2, float* __restrict__ OUT, int N) {
  int wid = (blockIdx.x * 256 + threadIdx.x) >> 6;
  int lane = threadIdx.x & 63;
  if (wid >= N) return;
  int p0 = rowptr[wid], p1 = rowptr[wid + 1];
  int grp = lane >> 3, li = lane & 7;       // li covers feats li*8..+7
  const size_t rowoff = (size_t)li * 8;
  float a0[8], a1[8];
  #pragma unroll
  for (int j = 0; j < 8; ++j) { a0[j] = 0.f; a1[j] = 0.f; }

  int p = p0;
  for (; p + 16 <= p1; p += 16) {
    int2 e0 = edges[p + grp];
    int2 e1 = edges[p + 8 + grp];
    uint4 h0 = *(const uint4*)(H2h + (size_t)e0.x * FO + rowoff);
    uint4 h1 = *(const uint4*)(H2h + (size_t)e1.x * FO + rowoff);
    float n0 = __int_as_float(e0.y), n1 = __int_as_float(e1.y);
    a0[0] += n0 * h2f(h0.x & 0xffffu); a0[1] += n0 * h2f(h0.x >> 16);
    a0[2] += n0 * h2f(h0.y & 0xffffu); a0[3] += n0 * h2f(h0.y >> 16);
    a0[4] += n0 * h2f(h0.z & 0xffffu); a0[5] += n0 * h2f(h0.z >> 16);
    a0[6] += n0 * h2f(h0.w & 0xffffu); a0[7] += n0 * h2f(h0.w >> 16);
    a1[0] += n1 * h2f(h1.x & 0xffffu); a1[1] += n1 * h2f(h1.x >> 16);
    a1[2] += n1 * h2f(h1.y & 0xffffu); a1[3] += n1 * h2f(h1.y >> 16);
    a1[4] += n1 * h2f(h1.z & 0xffffu); a1[5] += n1 * h2f(h1.z >> 16);
    a1[6] += n1 * h2f(h1.w & 0xffffu); a1[7] += n1 * h2f(h1.w >> 16);
  }
  for (; p + 8 <= p1; p += 8) {
    int2 e0 = edges[p + grp];
    uint4 h0 = *(const uint4*)(H2h + (size_t)e0.x * FO + rowoff);
    float n0 = __int_as_float(e0.y);
    a0[0] += n0 * h2f(h0.x & 0xffffu); a0[1] += n0 * h2f(h0.x >> 16);
    a0[2] += n0 * h2f(h0.y & 0xffffu); a0[3] += n0 * h2f(h0.y >> 16);
    a0[4] += n0 * h2f(h0.z & 0xffffu); a0[5] += n0 * h2f(h0.z >> 16);
    a0[6] += n0 * h2f(h0.w & 0xffffu); a0[7] += n0 * h2f(h0.w >> 16);
  }
  if (p < p1) {  // 1..7 leftover edges: masked
    int q = p + grp;
    int qi = (q < p1) ? q : p;
    int2 e0 = edges[qi];
    float n0 = (q < p1) ? __int_as_float(e0.y) : 0.f;
    uint4 h0 = *(const uint4*)(H2h + (size_t)e0.x * FO + rowoff);
    a0[0] += n0 * h2f(h0.x & 0xffffu); a0[1] += n0 * h2f(h0.x >> 16);
    a0[2] += n0 * h2f(h0.y & 0xffffu); a0[3] += n0 * h2f(h0.y >> 16);
    a0[4] += n0 * h2f(h0.z & 0xffffu); a0[5] += n0 * h2f(h0.z >> 16);
    a0[6] += n0 * h2f(h0.w & 0xffffu); a0[7] += n0 * h2f(h0.w >> 16);
  }
  float s[8];
  #pragma unroll
  for (int j = 0; j < 8; ++j) {
    s[j] = a0[j] + a1[j];
    s[j] += __shfl_xor(s[j], 8);
    s[j] += __shfl_xor(s[j], 16);
    s[j] += __shfl_xor(s[j], 32);
  }
  if (lane < 8) {
    float di = dinv[wid], sn = di * di;
    uint4 hs = *(const uint4*)(H2h + (size_t)wid * FO + rowoff);
    s[0] += sn * h2f(hs.x & 0xffffu); s[1] += sn * h2f(hs.x >> 16);
    s[2] += sn * h2f(hs.y & 0xffffu); s[3] += sn * h2f(hs.y >> 16);
    s[4] += sn * h2f(hs.z & 0xffffu); s[5] += sn * h2f(hs.z >> 16);
    s[6] += sn * h2f(hs.w & 0xffffu); s[7] += sn * h2f(hs.w >> 16);
    float4 bv0 = *(const float4*)(b2 + li * 8);
    float4 bv1 = *(const float4*)(b2 + li * 8 + 4);
    float4 o0 = make_float4(s[0] + bv0.x, s[1] + bv0.y, s[2] + bv0.z, s[3] + bv0.w);
    float4 o1 = make_float4(s[4] + bv1.x, s[5] + bv1.y, s[6] + bv1.z, s[7] + bv1.w);
    *(float4*)(OUT + (size_t)wid * FO + li * 8) = o0;
    *(float4*)(OUT + (size_t)wid * FO + li * 8 + 4) = o1;
  }
}

extern "C" void kernel_launch(void* const* d_in, const int* in_sizes, int n_in,
                              void* d_out, int out_size, void* d_ws, size_t ws_size,
                              hipStream_t stream) {
  const float* x  = (const float*)d_in[0];
  const int*   ei = (const int*)d_in[1];
  const float* ew = (const float*)d_in[2];
  const float* W1 = (const float*)d_in[3];
  const float* b1 = (const float*)d_in[4];
  const float* W2 = (const float*)d_in[5];
  const float* b2 = (const float*)d_in[6];
  float* out = (float*)d_out;

  const int N = in_sizes[0] / FIN;        // 100000
  const int E = in_sizes[2];              // 3200000
  const int* src = ei;
  const int* dst = ei + E;
  const int NBG = (N + 63) / 64;          // gemm1 tiles (1563)
  const int NBA = (E + EBLK - 1) / EBLK;  // A-phase blocks (391)
  const int NB  = (N + 255) / 256;        // buckets (391)
  const int L   = NB * NBA;               // gtable length (152,881)
  const int nsb = (L + 1023) / 1024;      // scan blocks (150, <=256)

  // workspace layout (16B-aligned slices), ~117MB total
  char* ws = (char*)d_ws;
  size_t off = 0;
  unsigned short* h1h = (unsigned short*)(ws + off); off += (size_t)N * FH * 2;  // fp16 h1
  unsigned short* h2h = (unsigned short*)(ws + off); off += (size_t)N * FO * 2;  // fp16 h2
  unsigned short* a1b = (unsigned short*)(ws + off); off += (size_t)N * FH * 2;  // bf16 a1
  int2*  edges  = (int2*) (ws + off); off += (size_t)E * 8;
  unsigned long long* bdw = (unsigned long long*)(ws + off); off += (size_t)E * 8;
  int*   gtable = (int*)  (ws + off); off += (((size_t)L * 4) + 15) & ~(size_t)15;
  int*   rowptr = (int*)  (ws + off); off += (((size_t)(N + 1) * 4) + 15) & ~(size_t)15;
  float* dinv   = (float*)(ws + off); off += (size_t)N * 4;
  int*   bsum   = (int*)  (ws + off); off += 1024;
  unsigned short* WT1 = (unsigned short*)(ws + off); off += (size_t)FH * FIN * 2;  // bf16 W1^T
  unsigned short* WT2 = (unsigned short*)(ws + off); off += (size_t)FO * FH * 2;   // bf16 W2^T

  // weight transpose + bf16 cvt (tiny, off critical path)
  prep_w_kernel<<<(FIN * FH + FH * FO + 255) / 256, 256, 0, stream>>>(W1, W2, WT1, WT2);
  // CSR build (LDS-atomic bucketed) + MFMA gemm1 fused
  a1hist_gemm1_kernel<<<NBA + NBG, 256, 0, stream>>>(dst, gtable, E, NBA, NB,
                                                     x, WT1, h1h, N, NBG);
  scan1i_kernel<<<nsb, 256, 0, stream>>>(gtable, bsum, L);
  scan2_kernel<<<1, 256, 0, stream>>>(bsum, nsb);
  scan3_kernel<<<(L + 255) / 256, 256, 0, stream>>>(gtable, bsum, L);
  a3_bucketize_kernel<<<NBA, 256, 0, stream>>>(src, dst, ew, gtable, bdw, E, NBA);
  b1_degree_kernel<<<NB, 256, 0, stream>>>(bdw, gtable, rowptr, dinv, E, NBA, NB, N);
  b2_scatter_kernel<<<NB, 256, 0, stream>>>(bdw, gtable, rowptr, dinv, edges,
                                            E, NBA, NB);
  // layers
  agg1_kernel<<<(N * 64 + 255) / 256, 256, 0, stream>>>(h1h, edges, rowptr,
                                                        dinv, b1, a1b, N);
  gemm2_kernel<<<(N + 63) / 64, 256, 0, stream>>>(a1b, WT2, h2h, N);
  agg2_kernel<<<(N * 64 + 255) / 256, 256, 0, stream>>>(h2h, edges, rowptr,
                                                        dinv, b2, out, N);
}